// Round 5
// baseline (409.234 us; speedup 1.0000x reference)
//
#include <hip/hip_runtime.h>
#include <hip/hip_bf16.h>
#include <math.h>

#define NT    4096
#define DM    768
#define HD    3072
#define NE    8
#define CAP   2048
// total compact rows: sum(roundup(min(cnt,CAP),128)) <= 8192 + 8*127 -> 9216
#define SLOTS_MAX 9216
// 256-row tile worklist: sum(ceil(min(cnt,CAP)/256)) <= 8192/256 + 7 = 39.
// 8 XCD bins x capacity 5 = 40 slots; wl[slot*8 + bin]; XCD = b%8 = wi%8 = bin.
#define WDIM2 40
#define BINCAP2 5

typedef __attribute__((ext_vector_type(8))) short bf16x8;
typedef __attribute__((ext_vector_type(4))) float f32x4;

__device__ __forceinline__ unsigned short f2bf(float f) {
  unsigned int u = __float_as_uint(f);
  unsigned int r = (u + 0x7fffu + ((u >> 16) & 1u)) >> 16;
  return (unsigned short)r;
}

__device__ __forceinline__ void async16(const unsigned short* g, unsigned short* l) {
  __builtin_amdgcn_global_load_lds((const __attribute__((address_space(1))) void*)g,
                                   (__attribute__((address_space(3))) void*)l,
                                   16, 0, 0);
}

// ---------------- convert x: fp32 -> bf16 --------------------------------------
__global__ void convert_x_kernel(const float* __restrict__ x,
                                 unsigned short* __restrict__ xb) {
  int i = (blockIdx.x * 256 + threadIdx.x) * 4;
  float4 v = *(const float4*)(x + i);
  uint2 o;
  o.x = (unsigned int)f2bf(v.x) | ((unsigned int)f2bf(v.y) << 16);
  o.y = (unsigned int)f2bf(v.z) | ((unsigned int)f2bf(v.w) << 16);
  *(uint2*)(xb + i) = o;
}

// ------ transpose+convert: dst_bf16[e][c][r] = src_f32[e][r][coloff + c] -------
// 256 src-rows x 64 src-cols per block. Reads: 256B segments (16 lanes x float4).
// LDS: row-pair packed uints, stride 129 (<=2-way banks both phases).
// Writes: 256B segments (16 lanes x uint4) -> full cachelines.
__global__ __launch_bounds__(256) void transpose_kernel(
    const float* __restrict__ src, unsigned short* __restrict__ dst,
    int R, int src_stride, int col_off,
    size_t src_e_stride, size_t dst_e_stride, int ncx) {
  __shared__ unsigned int tile32[64 * 129];
  const int b = blockIdx.x;
  const int e = b & 7;
  const int idx = b >> 3;
  const int c0 = (idx % ncx) * 64;
  const int r0 = (idx / ncx) * 256;
  const float* s = src + (size_t)e * src_e_stride + col_off;
  unsigned short* d = dst + (size_t)e * dst_e_stride;
  const int t = threadIdx.x;
  const int q16 = t & 15;       // col group (4 cols via float4)
  const int tg = t >> 4;        // 0..15
#pragma unroll
  for (int i = 0; i < 8; i++) {
    int rl = tg * 2 + i * 32;   // even rows 0..254
    const float4 f0 = *(const float4*)(s + (size_t)(r0 + rl) * src_stride + c0 + q16 * 4);
    const float4 f1 = *(const float4*)(s + (size_t)(r0 + rl + 1) * src_stride + c0 + q16 * 4);
    int j = tg + i * 16;        // packed row-pair index 0..127
    tile32[(q16 * 4 + 0) * 129 + j] = (unsigned int)f2bf(f0.x) | ((unsigned int)f2bf(f1.x) << 16);
    tile32[(q16 * 4 + 1) * 129 + j] = (unsigned int)f2bf(f0.y) | ((unsigned int)f2bf(f1.y) << 16);
    tile32[(q16 * 4 + 2) * 129 + j] = (unsigned int)f2bf(f0.z) | ((unsigned int)f2bf(f1.z) << 16);
    tile32[(q16 * 4 + 3) * 129 + j] = (unsigned int)f2bf(f0.w) | ((unsigned int)f2bf(f1.w) << 16);
  }
  __syncthreads();
#pragma unroll
  for (int i = 0; i < 4; i++) {
    int cl = tg + i * 16;       // dst row (src col) 0..63
    unsigned short* drow = d + (size_t)(c0 + cl) * R + r0;
#pragma unroll
    for (int half = 0; half < 2; half++) {
      int u = q16 * 4 + half * 64;
      uint4 v;
      v.x = tile32[cl * 129 + u + 0];
      v.y = tile32[cl * 129 + u + 1];
      v.z = tile32[cl * 129 + u + 2];
      v.w = tile32[cl * 129 + u + 3];
      *(uint4*)(drow + q16 * 8 + half * 128) = v;
    }
  }
}

// ---------------- gate dots: logits, top-2, softmax (NO atomics) ---------------
__global__ void gate_dots_kernel(const float* __restrict__ inp,
                                 const float* __restrict__ gw,
                                 const float* __restrict__ gb,
                                 int2* __restrict__ tope,
                                 float2* __restrict__ tops) {
  const int tok  = blockIdx.x * 4 + (threadIdx.x >> 6);
  const int lane = threadIdx.x & 63;
  const float* x = inp + (size_t)tok * DM;
  float acc[NE];
#pragma unroll
  for (int e = 0; e < NE; e++) acc[e] = 0.f;
  for (int d = lane; d < DM; d += 64) {
    float xv = x[d];
    const float4 w0 = *(const float4*)(gw + d * NE);
    const float4 w1v = *(const float4*)(gw + d * NE + 4);
    acc[0] += xv * w0.x; acc[1] += xv * w0.y;
    acc[2] += xv * w0.z; acc[3] += xv * w0.w;
    acc[4] += xv * w1v.x; acc[5] += xv * w1v.y;
    acc[6] += xv * w1v.z; acc[7] += xv * w1v.w;
  }
#pragma unroll
  for (int e = 0; e < NE; e++) {
    float v = acc[e];
#pragma unroll
    for (int m = 32; m > 0; m >>= 1) v += __shfl_xor(v, m, 64);
    acc[e] = v + gb[e];
  }
  if (lane == 0) {
    float bv = -1e30f, sv = -1e30f; int bi = 0, si = 0;
#pragma unroll
    for (int e = 0; e < NE; e++) {
      float v = acc[e];
      if (v > bv)      { sv = bv; si = bi; bv = v; bi = e; }
      else if (v > sv) { sv = v;  si = e; }
    }
    float e1 = expf(sv - bv);
    float s0 = 1.f / (1.f + e1);
    float s1 = e1 / (1.f + e1);
    tope[tok] = make_int2(bi, si);
    tops[tok] = make_float2(s0, s1);
  }
}

// -------- assign: slot positions, ballot-aggregated LDS atomics ----------------
__device__ __forceinline__ int agg_inc(int* lcnt, int key) {
  const int lane = threadIdx.x & 63;
  int p = 0;
#pragma unroll
  for (int ee = 0; ee < NE; ee++) {
    unsigned long long m = __ballot(key == ee);
    if (m) {
      int leader = __ffsll(m) - 1;
      int n = __popcll(m);
      int b = 0;
      if (lane == leader) b = atomicAdd(&lcnt[ee], n);
      b = __shfl(b, leader, 64);
      if (key == ee) p = b + __popcll(m & ((1ull << lane) - 1ull));
    }
  }
  return p;
}

__global__ void assign_kernel(const int2* __restrict__ tope,
                              int* __restrict__ cnt,
                              int* __restrict__ base,
                              int* __restrict__ src,
                              int2* __restrict__ pos,
                              int2* __restrict__ wl) {
  __shared__ int lcnt[NE];
  const int t = threadIdx.x;
  if (t < NE) lcnt[t] = 0;
  __syncthreads();
  for (int i = t; i < NT; i += 1024) {
    int2 e = tope[i];
    int p0 = agg_inc(lcnt, e.x);
    int p1 = agg_inc(lcnt, e.y);
    if (p0 < CAP) src[e.x * CAP + p0] = i;
    if (p1 < CAP) src[e.y * CAP + p1] = i;
    pos[i] = make_int2(p0, p1);
  }
  __syncthreads();
  if (t == 0) {
    int b = 0;
    for (int e = 0; e < NE; e++) {
      int c = min(lcnt[e], CAP);
      cnt[e] = c;
      base[e] = b;
      b += (c + 127) & ~127;
    }
    // Balanced-affinity worklist at 256-row granularity: fill 8 XCD bins
    // (capacity BINCAP2) in expert order -> each bin holds tiles of 1-2
    // experts (B-panel affinity) with max bin <= 5 (balance). XCD = wi%8.
    for (int s = 0; s < WDIM2; s++) wl[s] = make_int2(-1, 0);
    int bin = 0, fill = 0;
    for (int e = 0; e < NE; e++) {
      int ntl = (cnt[e] + 255) >> 8;
      for (int mt = 0; mt < ntl; mt++) {
        if (fill == BINCAP2) { bin++; fill = 0; }
        wl[fill * 8 + bin] = make_int2(e, mt * 256);
        fill++;
      }
    }
  }
}

// ---------------- GEMM1: h_c = gelu(gather(xb) @ w1_chunk + b1) ---------------
// 256x256x32 tiles, 512 threads (8 waves = 2M x 4N, 64x128-out each... wave
// owns 128 rows x 64 cols via acc[8][4]). Halves staging traffic vs 128-tiles
// (A staged N/256 times, B staged M/256 times) -> relieves the L3-BW ceiling.
// Depth-2 prefetch, 3 LDS buffers, counted vmcnt, both-sides kc XOR-swizzle
// (identical sync/swizzle algebra to the verified 128-tile loop).
__global__ __launch_bounds__(512) void gemm1_kernel(
    const unsigned short* __restrict__ xb,    // [NT][DM] bf16
    const unsigned short* __restrict__ w1t,   // [E][chunk][DM] bf16
    const float* __restrict__ b1,             // [E][HD] fp32
    const int* __restrict__ cnt,
    const int* __restrict__ base,
    const int* __restrict__ src,
    const int2* __restrict__ wl,
    unsigned short* __restrict__ h,           // [SLOTS_MAX][chunk] bf16
    int hoff, int chunk) {
  const int b = blockIdx.x;
  const int wi = b % WDIM2;
  const int nt = b / WDIM2;
  const int2 wle = wl[wi];
  if (wle.x < 0) return;
  const int e = wle.x;
  const int m0 = wle.y;
  const int n0 = nt * 256;
  const int count = cnt[e];
  const int cpad = (count + 127) & ~127;   // write guard: 128-padded row space
  const int hb = base[e];

  __shared__ unsigned short As[3 * 8192];   // 3 x [256][32]
  __shared__ unsigned short Bs[3 * 8192];

  const int t = threadIdx.x;
  const int lane = t & 63;
  const int wave = t >> 6;
  const int r0 = t >> 2;                    // 0..127
  // swizzled staging k-group: g_data = g_phys ^ ((row>>1)&3)
  const int kc = ((t & 3) ^ ((t >> 3) & 3)) * 8;

  const int tok0 = (m0 + r0       < count) ? src[e * CAP + m0 + r0]       : 0;
  const int tok1 = (m0 + r0 + 128 < count) ? src[e * CAP + m0 + r0 + 128] : 0;
  const unsigned short* aptr0 = xb + (size_t)tok0 * DM + kc;
  const unsigned short* aptr1 = xb + (size_t)tok1 * DM + kc;
  const unsigned short* w1e = w1t + (size_t)e * chunk * DM;
  const unsigned short* bptr0 = w1e + (size_t)(n0 + r0) * DM + kc;
  const unsigned short* bptr1 = bptr0 + (size_t)128 * DM;

  const int wrow = (wave >> 2) * 128;       // 2 M-groups of 128 rows
  const int wcol = (wave & 3) * 64;         // 4 N-groups of 64 cols
  const int lrow = lane & 15;
  // swizzled read k-offset (matches staging permutation; conflict-free)
  const int koff = ((lane >> 4) ^ ((lane >> 1) & 3)) * 8;

  f32x4 acc[8][4];
#pragma unroll
  for (int i = 0; i < 8; i++)
#pragma unroll
    for (int j = 0; j < 4; j++) acc[i][j] = (f32x4){0.f, 0.f, 0.f, 0.f};

#define STAGE1(bi, kk) do {                                   \
    unsigned short* A_ = As + (bi) * 8192 + wave * 512;       \
    unsigned short* B_ = Bs + (bi) * 8192 + wave * 512;       \
    async16(aptr0 + (kk), A_);                                \
    async16(aptr1 + (kk), A_ + 4096);                         \
    async16(bptr0 + (kk), B_);                                \
    async16(bptr1 + (kk), B_ + 4096);                         \
  } while (0)

#define COMPUTE1(bi) do {                                               \
    const unsigned short* A_ = As + (bi) * 8192;                        \
    const unsigned short* B_ = Bs + (bi) * 8192;                        \
    bf16x8 af[8], bfr[4];                                               \
    _Pragma("unroll")                                                   \
    for (int i = 0; i < 8; i++)                                         \
      af[i] = *(const bf16x8*)(A_ + (wrow + i * 16 + lrow) * 32 + koff);\
    _Pragma("unroll")                                                   \
    for (int j = 0; j < 4; j++)                                         \
      bfr[j] = *(const bf16x8*)(B_ + (wcol + j * 16 + lrow) * 32 + koff);\
    _Pragma("unroll")                                                   \
    for (int i = 0; i < 8; i++)                                         \
      _Pragma("unroll")                                                 \
      for (int j = 0; j < 4; j++)                                       \
        acc[i][j] = __builtin_amdgcn_mfma_f32_16x16x32_bf16(af[i], bfr[j], acc[i][j], 0, 0, 0); \
  } while (0)

  const int NS = DM / 32;   // 24 K-steps
  STAGE1(0, 0);
  STAGE1(1, 32);
  int cur = 0;
  for (int ts = 0; ts < NS - 2; ++ts) {
    int pf = cur + 2; if (pf >= 3) pf -= 3;
    STAGE1(pf, (ts + 2) * 32);
    asm volatile("s_waitcnt vmcnt(8)" ::: "memory");   // tile ts landed (own 4 oldest)
    __builtin_amdgcn_s_barrier();                       // landed for ALL waves
    COMPUTE1(cur);
    asm volatile("s_waitcnt lgkmcnt(0)" ::: "memory"); // reads retired before free
    __builtin_amdgcn_s_barrier();                       // buffer free for overwrite
    if (++cur == 3) cur = 0;
  }
  asm volatile("s_waitcnt vmcnt(4)" ::: "memory");
  __builtin_amdgcn_s_barrier();
  COMPUTE1(cur);
  if (++cur == 3) cur = 0;
  asm volatile("s_waitcnt vmcnt(0)" ::: "memory");
  __builtin_amdgcn_s_barrier();
  COMPUTE1(cur);

  const int q4 = (lane >> 4) * 4;
  const int c = lane & 15;
  unsigned short* hrow = h + (size_t)(hb + m0) * chunk + n0;
#pragma unroll
  for (int j = 0; j < 4; j++) {
    const float bias = b1[e * HD + hoff + n0 + wcol + j * 16 + c];
#pragma unroll
    for (int i = 0; i < 8; i++) {
#pragma unroll
      for (int r = 0; r < 4; r++) {
        int m = wrow + i * 16 + q4 + r;
        if (m0 + m < cpad) {
          float v = acc[i][j][r] + bias;
          // exact identity: 0.5*v*(1+tanh(u)) == v * sigmoid(2u)
          float u2 = 1.5957691216f * (v + 0.044715f * v * v * v);
          float g = v / (1.f + __expf(-u2));
          hrow[(size_t)m * chunk + wcol + j * 16 + c] = f2bf(g);
        }
      }
    }
  }
#undef STAGE1
#undef COMPUTE1
}

// -------- GEMM2 split-K: ye_part[kh][slot] = h_half @ w2_half (+ prev) ---------
// 256x256x32 tiles; b = fast*WDIM2 + wi, fast = kh*3 + n-tile. XCD = wi%8.
__global__ __launch_bounds__(512) void gemm2_kernel(
    const unsigned short* __restrict__ h,     // [SLOTS_MAX][chunk] bf16
    const unsigned short* __restrict__ w2t,   // [E][DM][chunk] bf16
    const int* __restrict__ cnt,
    const int* __restrict__ base,
    const int2* __restrict__ wl,
    float* __restrict__ ye,                   // [2][SLOTS_MAX][DM] fp32
    int chunk, int add_prev) {
  const int b = blockIdx.x;
  const int wi = b % WDIM2;
  const int fast = b / WDIM2;            // 0..5
  const int2 wle = wl[wi];
  if (wle.x < 0) return;
  const int e = wle.x;
  const int m0 = wle.y;
  const int kh = fast / 3;
  const int n0 = (fast % 3) * 256;
  const int count = cnt[e];
  const int cpad = (count + 127) & ~127;
  const int hb = base[e];
  const int khalf = chunk >> 1;

  __shared__ unsigned short As[3 * 8192];
  __shared__ unsigned short Bs[3 * 8192];

  const int t = threadIdx.x;
  const int lane = t & 63;
  const int wave = t >> 6;
  const int r0 = t >> 2;
  const int kc = ((t & 3) ^ ((t >> 3) & 3)) * 8;

  const unsigned short* aptr0 = h + (size_t)(hb + m0 + r0) * chunk + kh * khalf + kc;
  const unsigned short* aptr1 = aptr0 + (size_t)128 * chunk;
  const unsigned short* w2e = w2t + (size_t)e * DM * chunk;
  const unsigned short* bptr0 = w2e + (size_t)(n0 + r0) * chunk + kh * khalf + kc;
  const unsigned short* bptr1 = bptr0 + (size_t)128 * chunk;

  const int wrow = (wave >> 2) * 128;
  const int wcol = (wave & 3) * 64;
  const int lrow = lane & 15;
  const int koff = ((lane >> 4) ^ ((lane >> 1) & 3)) * 8;

  f32x4 acc[8][4];
#pragma unroll
  for (int i = 0; i < 8; i++)
#pragma unroll
    for (int j = 0; j < 4; j++) acc[i][j] = (f32x4){0.f, 0.f, 0.f, 0.f};

#define STAGE2(bi, kk) do {                                   \
    unsigned short* A_ = As + (bi) * 8192 + wave * 512;       \
    unsigned short* B_ = Bs + (bi) * 8192 + wave * 512;       \
    async16(aptr0 + (kk), A_);                                \
    async16(aptr1 + (kk), A_ + 4096);                         \
    async16(bptr0 + (kk), B_);                                \
    async16(bptr1 + (kk), B_ + 4096);                         \
  } while (0)

#define COMPUTE2(bi) do {                                               \
    const unsigned short* A_ = As + (bi) * 8192;                        \
    const unsigned short* B_ = Bs + (bi) * 8192;                        \
    bf16x8 af[8], bfr[4];                                               \
    _Pragma("unroll")                                                   \
    for (int i = 0; i < 8; i++)                                         \
      af[i] = *(const bf16x8*)(A_ + (wrow + i * 16 + lrow) * 32 + koff);\
    _Pragma("unroll")                                                   \
    for (int j = 0; j < 4; j++)                                         \
      bfr[j] = *(const bf16x8*)(B_ + (wcol + j * 16 + lrow) * 32 + koff);\
    _Pragma("unroll")                                                   \
    for (int i = 0; i < 8; i++)                                         \
      _Pragma("unroll")                                                 \
      for (int j = 0; j < 4; j++)                                       \
        acc[i][j] = __builtin_amdgcn_mfma_f32_16x16x32_bf16(af[i], bfr[j], acc[i][j], 0, 0, 0); \
  } while (0)

  const int NS = khalf >> 5;            // 48 for chunk=3072
  STAGE2(0, 0);
  STAGE2(1, 32);
  int cur = 0;
  for (int ts = 0; ts < NS - 2; ++ts) {
    int pf = cur + 2; if (pf >= 3) pf -= 3;
    STAGE2(pf, (ts + 2) * 32);
    asm volatile("s_waitcnt vmcnt(8)" ::: "memory");
    __builtin_amdgcn_s_barrier();
    COMPUTE2(cur);
    asm volatile("s_waitcnt lgkmcnt(0)" ::: "memory");
    __builtin_amdgcn_s_barrier();
    if (++cur == 3) cur = 0;
  }
  asm volatile("s_waitcnt vmcnt(4)" ::: "memory");
  __builtin_amdgcn_s_barrier();
  COMPUTE2(cur);
  if (++cur == 3) cur = 0;
  asm volatile("s_waitcnt vmcnt(0)" ::: "memory");
  __builtin_amdgcn_s_barrier();
  COMPUTE2(cur);

  const int q4 = (lane >> 4) * 4;
  const int c = lane & 15;
  float* yrow = ye + (size_t)kh * SLOTS_MAX * DM + (size_t)(hb + m0) * DM + n0;
#pragma unroll
  for (int i = 0; i < 8; i++) {
#pragma unroll
    for (int r = 0; r < 4; r++) {
      int m = wrow + i * 16 + q4 + r;
      if (m0 + m < cpad) {
#pragma unroll
        for (int j = 0; j < 4; j++) {
          int n = wcol + j * 16 + c;
          float v = acc[i][j][r];
          if (add_prev) v += yrow[(size_t)m * DM + n];
          yrow[(size_t)m * DM + n] = v;
        }
      }
    }
  }
#undef STAGE2
#undef COMPUTE2
}

// ------- gather: out[tok] = s0*(ye0+ye1+b2)[gs0] + s1*(ye0+ye1+b2)[gs1] --------
__global__ void gather_kernel(const float* __restrict__ ye,
                              const float* __restrict__ b2,
                              const int2* __restrict__ tope,
                              const float2* __restrict__ tops,
                              const int2* __restrict__ pos,
                              const int* __restrict__ base,
                              float* __restrict__ out) {
  int idx = blockIdx.x * 256 + threadIdx.x;
  int tok = idx / (DM / 4);
  int d4 = (idx % (DM / 4)) * 4;
  int2 e = tope[tok];
  float2 s = tops[tok];
  int2 p = pos[tok];
  const float* ye1 = ye + (size_t)SLOTS_MAX * DM;
  float4 r = make_float4(0.f, 0.f, 0.f, 0.f);
  if (p.x < CAP) {
    size_t row = (size_t)(base[e.x] + p.x) * DM + d4;
    const float4 va = *(const float4*)(ye + row);
    const float4 vb = *(const float4*)(ye1 + row);
    const float4 bb = *(const float4*)(b2 + e.x * DM + d4);
    r.x += s.x * (va.x + vb.x + bb.x); r.y += s.x * (va.y + vb.y + bb.y);
    r.z += s.x * (va.z + vb.z + bb.z); r.w += s.x * (va.w + vb.w + bb.w);
  }
  if (p.y < CAP) {
    size_t row = (size_t)(base[e.y] + p.y) * DM + d4;
    const float4 va = *(const float4*)(ye + row);
    const float4 vb = *(const float4*)(ye1 + row);
    const float4 bb = *(const float4*)(b2 + e.y * DM + d4);
    r.x += s.y * (va.x + vb.x + bb.x); r.y += s.y * (va.y + vb.y + bb.y);
    r.z += s.y * (va.z + vb.z + bb.z); r.w += s.y * (va.w + vb.w + bb.w);
  }
  *(float4*)(out + (size_t)tok * DM + d4) = r;
}

extern "C" void kernel_launch(void* const* d_in, const int* in_sizes, int n_in,
                              void* d_out, int out_size, void* d_ws, size_t ws_size,
                              hipStream_t stream) {
  const float* inp = (const float*)d_in[0];
  const float* gw  = (const float*)d_in[1];
  const float* gb  = (const float*)d_in[2];
  const float* w1  = (const float*)d_in[3];
  const float* b1  = (const float*)d_in[4];
  const float* w2  = (const float*)d_in[5];
  const float* b2  = (const float*)d_in[6];
  float* out = (float*)d_out;

  const size_t meta = 165376;
  // chunk selection: one SHARED transposed-weight buffer (w1t/w2t sequential).
  // chunk must be a multiple of 256 (transpose r-tiling, gemm1 n-tiles).
  const int cands[6] = {3072, 1536, 1024, 768, 512, 256};
  int chunk = 256;
  for (int ci = 0; ci < 6; ci++) {
    int c = cands[ci];
    size_t need = meta + (size_t)NT * DM * 2                 // xb
                + (size_t)NE * c * DM * 2                    // shared wt
                + (size_t)SLOTS_MAX * c * 2                  // h
                + 2 * (size_t)SLOTS_MAX * DM * 4;            // ye (2 partials)
    if (need <= ws_size) { chunk = c; break; }
  }

  char* ws = (char*)d_ws;
  int*    cnt  = (int*)(ws);              // 256 B
  int*    base = (int*)(ws + 256);        // 256 B
  int*    srcb = (int*)(ws + 512);        // 64 KB  -> 66048
  int2*   tope = (int2*)(ws + 66048);     // 32 KB  -> 98816
  float2* tops = (float2*)(ws + 98816);   // 32 KB  -> 131584
  int2*   pos  = (int2*)(ws + 131584);    // 32 KB  -> 164352
  int2*   wl   = (int2*)(ws + 164352);    // 320 B (40 entries)
  size_t off = meta;
  unsigned short* xb = (unsigned short*)(ws + off);  off += (size_t)NT * DM * 2;
  unsigned short* wt = (unsigned short*)(ws + off);  off += (size_t)NE * chunk * DM * 2;
  unsigned short* hc = (unsigned short*)(ws + off);  off += (size_t)SLOTS_MAX * chunk * 2;
  float* ye = (float*)(ws + off);

  convert_x_kernel<<<(NT * DM) / 1024, 256, 0, stream>>>(inp, xb);
  gate_dots_kernel<<<NT / 4, 256, 0, stream>>>(inp, gw, gb, tope, tops);
  assign_kernel<<<1, 1024, 0, stream>>>(tope, cnt, base, srcb, pos, wl);

  for (int c = 0; c < HD; c += chunk) {
    // w1 chunk into shared wt: wt[e][h_local][d] = w1[e][d][c + h_local]
    transpose_kernel<<<NE * (chunk / 64) * (DM / 256), 256, 0, stream>>>(
        w1, wt, DM, HD, c, (size_t)DM * HD, (size_t)chunk * DM, chunk / 64);
    gemm1_kernel<<<(chunk / 256) * WDIM2, 512, 0, stream>>>(
        xb, wt, b1, cnt, base, srcb, wl, hc, c, chunk);
    // w2 chunk into the SAME wt: wt[e][d][h_local] = w2[e][c + h_local][d]
    transpose_kernel<<<NE * (DM / 64) * (chunk / 256), 256, 0, stream>>>(
        w2 + (size_t)c * DM, wt, chunk, DM, 0, (size_t)HD * DM, (size_t)DM * chunk, DM / 64);
    gemm2_kernel<<<(2 * DM / 256) * WDIM2, 512, 0, stream>>>(
        hc, wt, cnt, base, wl, ye, chunk, c == 0 ? 0 : 1);
  }

  gather_kernel<<<(NT * DM / 4) / 256, 256, 0, stream>>>(ye, b2, tope, tops, pos, base, out);
}

// Round 6
// 382.007 us; speedup vs baseline: 1.0713x; 1.0713x over previous
//
#include <hip/hip_runtime.h>
#include <hip/hip_bf16.h>
#include <math.h>

#define NT    4096
#define DM    768
#define HD    3072
#define NE    8
#define CAP   2048
// total compact rows: sum(roundup(min(cnt,CAP),128)) <= 8192 + 8*127 -> 9216
#define SLOTS_MAX 9216
// 128-row tile worklist (gemm1): <= 71 entries; 8 bins x 9 = 72
#define WDIM1 72
#define BINCAP1 9
// 256-row tile worklist (gemm2): <= 39 entries; 8 bins x 5 = 40
#define WDIM2 40
#define BINCAP2 5

typedef __attribute__((ext_vector_type(8))) short bf16x8;
typedef __attribute__((ext_vector_type(4))) float f32x4;

__device__ __forceinline__ unsigned short f2bf(float f) {
  unsigned int u = __float_as_uint(f);
  unsigned int r = (u + 0x7fffu + ((u >> 16) & 1u)) >> 16;
  return (unsigned short)r;
}

__device__ __forceinline__ void async16(const unsigned short* g, unsigned short* l) {
  __builtin_amdgcn_global_load_lds((const __attribute__((address_space(1))) void*)g,
                                   (__attribute__((address_space(3))) void*)l,
                                   16, 0, 0);
}

// ---------------- convert x: fp32 -> bf16 --------------------------------------
__global__ void convert_x_kernel(const float* __restrict__ x,
                                 unsigned short* __restrict__ xb) {
  int i = (blockIdx.x * 256 + threadIdx.x) * 4;
  float4 v = *(const float4*)(x + i);
  uint2 o;
  o.x = (unsigned int)f2bf(v.x) | ((unsigned int)f2bf(v.y) << 16);
  o.y = (unsigned int)f2bf(v.z) | ((unsigned int)f2bf(v.w) << 16);
  *(uint2*)(xb + i) = o;
}

// ------ transpose+convert: dst_bf16[e][c][r] = src_f32[e][r][coloff + c] -------
// 256 src-rows x 64 src-cols per block. Reads: 256B segments (16 lanes x float4).
// LDS: row-pair packed uints, stride 129 (<=2-way banks both phases).
// Writes: 256B segments (16 lanes x uint4) -> full cachelines.
__global__ __launch_bounds__(256) void transpose_kernel(
    const float* __restrict__ src, unsigned short* __restrict__ dst,
    int R, int src_stride, int col_off,
    size_t src_e_stride, size_t dst_e_stride, int ncx) {
  __shared__ unsigned int tile32[64 * 129];
  const int b = blockIdx.x;
  const int e = b & 7;
  const int idx = b >> 3;
  const int c0 = (idx % ncx) * 64;
  const int r0 = (idx / ncx) * 256;
  const float* s = src + (size_t)e * src_e_stride + col_off;
  unsigned short* d = dst + (size_t)e * dst_e_stride;
  const int t = threadIdx.x;
  const int q16 = t & 15;       // col group (4 cols via float4)
  const int tg = t >> 4;        // 0..15
#pragma unroll
  for (int i = 0; i < 8; i++) {
    int rl = tg * 2 + i * 32;   // even rows 0..254
    const float4 f0 = *(const float4*)(s + (size_t)(r0 + rl) * src_stride + c0 + q16 * 4);
    const float4 f1 = *(const float4*)(s + (size_t)(r0 + rl + 1) * src_stride + c0 + q16 * 4);
    int j = tg + i * 16;        // packed row-pair index 0..127
    tile32[(q16 * 4 + 0) * 129 + j] = (unsigned int)f2bf(f0.x) | ((unsigned int)f2bf(f1.x) << 16);
    tile32[(q16 * 4 + 1) * 129 + j] = (unsigned int)f2bf(f0.y) | ((unsigned int)f2bf(f1.y) << 16);
    tile32[(q16 * 4 + 2) * 129 + j] = (unsigned int)f2bf(f0.z) | ((unsigned int)f2bf(f1.z) << 16);
    tile32[(q16 * 4 + 3) * 129 + j] = (unsigned int)f2bf(f0.w) | ((unsigned int)f2bf(f1.w) << 16);
  }
  __syncthreads();
#pragma unroll
  for (int i = 0; i < 4; i++) {
    int cl = tg + i * 16;       // dst row (src col) 0..63
    unsigned short* drow = d + (size_t)(c0 + cl) * R + r0;
#pragma unroll
    for (int half = 0; half < 2; half++) {
      int u = q16 * 4 + half * 64;
      uint4 v;
      v.x = tile32[cl * 129 + u + 0];
      v.y = tile32[cl * 129 + u + 1];
      v.z = tile32[cl * 129 + u + 2];
      v.w = tile32[cl * 129 + u + 3];
      *(uint4*)(drow + q16 * 8 + half * 128) = v;
    }
  }
}

// ---------------- gate dots: logits, top-2, softmax (NO atomics) ---------------
__global__ void gate_dots_kernel(const float* __restrict__ inp,
                                 const float* __restrict__ gw,
                                 const float* __restrict__ gb,
                                 int2* __restrict__ tope,
                                 float2* __restrict__ tops) {
  const int tok  = blockIdx.x * 4 + (threadIdx.x >> 6);
  const int lane = threadIdx.x & 63;
  const float* x = inp + (size_t)tok * DM;
  float acc[NE];
#pragma unroll
  for (int e = 0; e < NE; e++) acc[e] = 0.f;
  for (int d = lane; d < DM; d += 64) {
    float xv = x[d];
    const float4 w0 = *(const float4*)(gw + d * NE);
    const float4 w1v = *(const float4*)(gw + d * NE + 4);
    acc[0] += xv * w0.x; acc[1] += xv * w0.y;
    acc[2] += xv * w0.z; acc[3] += xv * w0.w;
    acc[4] += xv * w1v.x; acc[5] += xv * w1v.y;
    acc[6] += xv * w1v.z; acc[7] += xv * w1v.w;
  }
#pragma unroll
  for (int e = 0; e < NE; e++) {
    float v = acc[e];
#pragma unroll
    for (int m = 32; m > 0; m >>= 1) v += __shfl_xor(v, m, 64);
    acc[e] = v + gb[e];
  }
  if (lane == 0) {
    float bv = -1e30f, sv = -1e30f; int bi = 0, si = 0;
#pragma unroll
    for (int e = 0; e < NE; e++) {
      float v = acc[e];
      if (v > bv)      { sv = bv; si = bi; bv = v; bi = e; }
      else if (v > sv) { sv = v;  si = e; }
    }
    float e1 = expf(sv - bv);
    float s0 = 1.f / (1.f + e1);
    float s1 = e1 / (1.f + e1);
    tope[tok] = make_int2(bi, si);
    tops[tok] = make_float2(s0, s1);
  }
}

// -------- assign: slot positions, ballot-aggregated LDS atomics ----------------
__device__ __forceinline__ int agg_inc(int* lcnt, int key) {
  const int lane = threadIdx.x & 63;
  int p = 0;
#pragma unroll
  for (int ee = 0; ee < NE; ee++) {
    unsigned long long m = __ballot(key == ee);
    if (m) {
      int leader = __ffsll(m) - 1;
      int n = __popcll(m);
      int b = 0;
      if (lane == leader) b = atomicAdd(&lcnt[ee], n);
      b = __shfl(b, leader, 64);
      if (key == ee) p = b + __popcll(m & ((1ull << lane) - 1ull));
    }
  }
  return p;
}

__global__ void assign_kernel(const int2* __restrict__ tope,
                              int* __restrict__ cnt,
                              int* __restrict__ base,
                              int* __restrict__ src,
                              int2* __restrict__ pos,
                              int2* __restrict__ wl1,
                              int2* __restrict__ wl2) {
  __shared__ int lcnt[NE];
  const int t = threadIdx.x;
  if (t < NE) lcnt[t] = 0;
  __syncthreads();
  for (int i = t; i < NT; i += 1024) {
    int2 e = tope[i];
    int p0 = agg_inc(lcnt, e.x);
    int p1 = agg_inc(lcnt, e.y);
    if (p0 < CAP) src[e.x * CAP + p0] = i;
    if (p1 < CAP) src[e.y * CAP + p1] = i;
    pos[i] = make_int2(p0, p1);
  }
  __syncthreads();
  if (t == 0) {
    int b = 0;
    for (int e = 0; e < NE; e++) {
      int c = min(lcnt[e], CAP);
      cnt[e] = c;
      base[e] = b;
      b += (c + 127) & ~127;
    }
    // Balanced-affinity worklists: fill 8 XCD bins in expert order -> each bin
    // holds tiles of 1-2 experts (B-panel L2 affinity) with balanced makespan.
    // wl[slot*8 + bin]; XCD = blockIdx%8 = wi%8 = bin.
    for (int s = 0; s < WDIM1; s++) wl1[s] = make_int2(-1, 0);
    int bin = 0, fill = 0;
    for (int e = 0; e < NE; e++) {
      int ntl = (cnt[e] + 127) >> 7;
      for (int mt = 0; mt < ntl; mt++) {
        if (fill == BINCAP1) { bin++; fill = 0; }
        wl1[fill * 8 + bin] = make_int2(e, mt * 128);
        fill++;
      }
    }
    for (int s = 0; s < WDIM2; s++) wl2[s] = make_int2(-1, 0);
    bin = 0; fill = 0;
    for (int e = 0; e < NE; e++) {
      int ntl = (cnt[e] + 255) >> 8;
      for (int mt = 0; mt < ntl; mt++) {
        if (fill == BINCAP2) { bin++; fill = 0; }
        wl2[fill * 8 + bin] = make_int2(e, mt * 256);
        fill++;
      }
    }
  }
}

// ---------------- GEMM1: h_c = gelu(gather(xb) @ w1_chunk + b1) ---------------
// 128x128x32, 256 thr, 48KB 3-buf LDS (3 blocks/CU), depth-2 counted vmcnt,
// both-sides kc XOR-swizzle (conflict-free). Epilogue stages C through LDS so
// hc writes are 128B contiguous segments (fixes measured 2x write-amp:
// 2B scattered stores -> 32B segments -> 90-108MB written vs 56.6 ideal).
__global__ __launch_bounds__(256) void gemm1_kernel(
    const unsigned short* __restrict__ xb,    // [NT][DM] bf16
    const unsigned short* __restrict__ w1t,   // [E][chunk][DM] bf16
    const float* __restrict__ b1,             // [E][HD] fp32
    const int* __restrict__ cnt,
    const int* __restrict__ base,
    const int* __restrict__ src,
    const int2* __restrict__ wl,
    unsigned short* __restrict__ h,           // [SLOTS_MAX][chunk] bf16
    int hoff, int chunk) {
  const int b = blockIdx.x;
  const int wi = b % WDIM1;
  const int nt = b / WDIM1;
  const int2 wle = wl[wi];
  if (wle.x < 0) return;
  const int e = wle.x;
  const int m0 = wle.y;
  const int n0 = nt * 128;
  const int count = cnt[e];
  const int hb = base[e];

  __shared__ unsigned short As[3 * 4096];   // 3 x [128][32]
  __shared__ unsigned short Bs[3 * 4096];

  const int t = threadIdx.x;
  const int lane = t & 63;
  const int wave = t >> 6;
  const int r0 = t >> 2;
  // swizzled staging k-group: g_data = g_phys ^ ((row>>1)&3)
  const int kc = ((t & 3) ^ ((t >> 3) & 3)) * 8;

  const int tok0 = (m0 + r0      < count) ? src[e * CAP + m0 + r0]      : 0;
  const int tok1 = (m0 + r0 + 64 < count) ? src[e * CAP + m0 + r0 + 64] : 0;
  const unsigned short* aptr0 = xb + (size_t)tok0 * DM + kc;
  const unsigned short* aptr1 = xb + (size_t)tok1 * DM + kc;
  const unsigned short* w1e = w1t + (size_t)e * chunk * DM;
  const unsigned short* bptr0 = w1e + (size_t)(n0 + r0) * DM + kc;
  const unsigned short* bptr1 = bptr0 + (size_t)64 * DM;

  const int wrow = (wave >> 1) * 64;
  const int wcol = (wave & 1) * 64;
  const int lrow = lane & 15;
  // swizzled read k-offset (matches staging permutation; conflict-free)
  const int koff = ((lane >> 4) ^ ((lane >> 1) & 3)) * 8;

  f32x4 acc[4][4];
#pragma unroll
  for (int i = 0; i < 4; i++)
#pragma unroll
    for (int j = 0; j < 4; j++) acc[i][j] = (f32x4){0.f, 0.f, 0.f, 0.f};

#define STAGE1(bi, kk) do {                                   \
    unsigned short* A_ = As + (bi) * 4096 + wave * 512;       \
    unsigned short* B_ = Bs + (bi) * 4096 + wave * 512;       \
    async16(aptr0 + (kk), A_);                                \
    async16(aptr1 + (kk), A_ + 2048);                         \
    async16(bptr0 + (kk), B_);                                \
    async16(bptr1 + (kk), B_ + 2048);                         \
  } while (0)

#define COMPUTE1(bi) do {                                               \
    const unsigned short* A_ = As + (bi) * 4096;                        \
    const unsigned short* B_ = Bs + (bi) * 4096;                        \
    bf16x8 af[4], bfr[4];                                               \
    _Pragma("unroll")                                                   \
    for (int i = 0; i < 4; i++)                                         \
      af[i] = *(const bf16x8*)(A_ + (wrow + i * 16 + lrow) * 32 + koff);\
    _Pragma("unroll")                                                   \
    for (int j = 0; j < 4; j++)                                         \
      bfr[j] = *(const bf16x8*)(B_ + (wcol + j * 16 + lrow) * 32 + koff);\
    _Pragma("unroll")                                                   \
    for (int i = 0; i < 4; i++)                                         \
      _Pragma("unroll")                                                 \
      for (int j = 0; j < 4; j++)                                       \
        acc[i][j] = __builtin_amdgcn_mfma_f32_16x16x32_bf16(af[i], bfr[j], acc[i][j], 0, 0, 0); \
  } while (0)

  const int NS = DM / 32;   // 24 K-steps
  STAGE1(0, 0);
  STAGE1(1, 32);
  int cur = 0;
  for (int ts = 0; ts < NS - 2; ++ts) {
    int pf = cur + 2; if (pf >= 3) pf -= 3;
    STAGE1(pf, (ts + 2) * 32);
    asm volatile("s_waitcnt vmcnt(8)" ::: "memory");   // tile ts landed (own 4 oldest)
    __builtin_amdgcn_s_barrier();                       // landed for ALL waves
    COMPUTE1(cur);
    asm volatile("s_waitcnt lgkmcnt(0)" ::: "memory"); // reads retired before free
    __builtin_amdgcn_s_barrier();                       // buffer free for overwrite
    if (++cur == 3) cur = 0;
  }
  asm volatile("s_waitcnt vmcnt(4)" ::: "memory");
  __builtin_amdgcn_s_barrier();
  COMPUTE1(cur);
  if (++cur == 3) cur = 0;
  asm volatile("s_waitcnt vmcnt(0)" ::: "memory");
  __builtin_amdgcn_s_barrier();
  COMPUTE1(cur);

  // ---- epilogue: gelu + LDS-staged coalesced store (128B segments) ----
  __syncthreads();   // all waves done reading As/Bs; safe to reuse as C slab
  const int q4 = (lane >> 4) * 4;
  const int c = lane & 15;
  // per-wave slab: 64 rows x 72 shorts (144B rows -> 16B aligned reads)
  unsigned short* slab = (wave < 2) ? (As + wave * 4608) : (Bs + (wave - 2) * 4608);
#pragma unroll
  for (int j = 0; j < 4; j++) {
    const float bias = b1[e * HD + hoff + n0 + wcol + j * 16 + c];
#pragma unroll
    for (int i = 0; i < 4; i++) {
#pragma unroll
      for (int r = 0; r < 4; r++) {
        float v = acc[i][j][r] + bias;
        // exact identity: 0.5*v*(1+tanh(u)) == v * sigmoid(2u)
        float u2 = 1.5957691216f * (v + 0.044715f * v * v * v);
        float g = v / (1.f + __expf(-u2));
        slab[(i * 16 + q4 + r) * 72 + j * 16 + c] = f2bf(g);
      }
    }
  }
  asm volatile("s_waitcnt lgkmcnt(0)" ::: "memory");  // own writes visible (own slab only)
  const int l8 = lane & 7;
  const int r8 = lane >> 3;
  unsigned short* hrow = h + (size_t)(hb + m0 + wrow) * chunk + n0 + wcol;
#pragma unroll
  for (int p = 0; p < 8; p++) {
    int lm = p * 8 + r8;
    uint4 v = *(const uint4*)(slab + lm * 72 + l8 * 8);
    *(uint4*)(hrow + (size_t)lm * chunk + l8 * 8) = v;
  }
#undef STAGE1
#undef COMPUTE1
}

// -------- GEMM2 split-K: ye_part[kh][slot] = h_half @ w2_half (+ prev) ---------
// 256x256x32 tiles, 512 thr (8 waves 2Mx4N), 96KB 3-buf LDS, depth-2 counted
// vmcnt, kc XOR-swizzle. b = fast*WDIM2 + wi, fast = kh*3 + n-tile; XCD = wi%8.
__global__ __launch_bounds__(512) void gemm2_kernel(
    const unsigned short* __restrict__ h,     // [SLOTS_MAX][chunk] bf16
    const unsigned short* __restrict__ w2t,   // [E][DM][chunk] bf16
    const int* __restrict__ cnt,
    const int* __restrict__ base,
    const int2* __restrict__ wl,
    float* __restrict__ ye,                   // [2][SLOTS_MAX][DM] fp32
    int chunk, int add_prev) {
  const int b = blockIdx.x;
  const int wi = b % WDIM2;
  const int fast = b / WDIM2;            // 0..5
  const int2 wle = wl[wi];
  if (wle.x < 0) return;
  const int e = wle.x;
  const int m0 = wle.y;
  const int kh = fast / 3;
  const int n0 = (fast % 3) * 256;
  const int count = cnt[e];
  const int cpad = (count + 127) & ~127;
  const int hb = base[e];
  const int khalf = chunk >> 1;

  __shared__ unsigned short As[3 * 8192];
  __shared__ unsigned short Bs[3 * 8192];

  const int t = threadIdx.x;
  const int lane = t & 63;
  const int wave = t >> 6;
  const int r0 = t >> 2;
  const int kc = ((t & 3) ^ ((t >> 3) & 3)) * 8;

  const unsigned short* aptr0 = h + (size_t)(hb + m0 + r0) * chunk + kh * khalf + kc;
  const unsigned short* aptr1 = aptr0 + (size_t)128 * chunk;
  const unsigned short* w2e = w2t + (size_t)e * DM * chunk;
  const unsigned short* bptr0 = w2e + (size_t)(n0 + r0) * chunk + kh * khalf + kc;
  const unsigned short* bptr1 = bptr0 + (size_t)128 * chunk;

  const int wrow = (wave >> 2) * 128;
  const int wcol = (wave & 3) * 64;
  const int lrow = lane & 15;
  const int koff = ((lane >> 4) ^ ((lane >> 1) & 3)) * 8;

  f32x4 acc[8][4];
#pragma unroll
  for (int i = 0; i < 8; i++)
#pragma unroll
    for (int j = 0; j < 4; j++) acc[i][j] = (f32x4){0.f, 0.f, 0.f, 0.f};

#define STAGE2(bi, kk) do {                                   \
    unsigned short* A_ = As + (bi) * 8192 + wave * 512;       \
    unsigned short* B_ = Bs + (bi) * 8192 + wave * 512;       \
    async16(aptr0 + (kk), A_);                                \
    async16(aptr1 + (kk), A_ + 4096);                         \
    async16(bptr0 + (kk), B_);                                \
    async16(bptr1 + (kk), B_ + 4096);                         \
  } while (0)

#define COMPUTE2(bi) do {                                               \
    const unsigned short* A_ = As + (bi) * 8192;                        \
    const unsigned short* B_ = Bs + (bi) * 8192;                        \
    bf16x8 af[8], bfr[4];                                               \
    _Pragma("unroll")                                                   \
    for (int i = 0; i < 8; i++)                                         \
      af[i] = *(const bf16x8*)(A_ + (wrow + i * 16 + lrow) * 32 + koff);\
    _Pragma("unroll")                                                   \
    for (int j = 0; j < 4; j++)                                         \
      bfr[j] = *(const bf16x8*)(B_ + (wcol + j * 16 + lrow) * 32 + koff);\
    _Pragma("unroll")                                                   \
    for (int i = 0; i < 8; i++)                                         \
      _Pragma("unroll")                                                 \
      for (int j = 0; j < 4; j++)                                       \
        acc[i][j] = __builtin_amdgcn_mfma_f32_16x16x32_bf16(af[i], bfr[j], acc[i][j], 0, 0, 0); \
  } while (0)

  const int NS = khalf >> 5;            // 48 for chunk=3072
  STAGE2(0, 0);
  STAGE2(1, 32);
  int cur = 0;
  for (int ts = 0; ts < NS - 2; ++ts) {
    int pf = cur + 2; if (pf >= 3) pf -= 3;
    STAGE2(pf, (ts + 2) * 32);
    asm volatile("s_waitcnt vmcnt(8)" ::: "memory");
    __builtin_amdgcn_s_barrier();
    COMPUTE2(cur);
    asm volatile("s_waitcnt lgkmcnt(0)" ::: "memory");
    __builtin_amdgcn_s_barrier();
    if (++cur == 3) cur = 0;
  }
  asm volatile("s_waitcnt vmcnt(4)" ::: "memory");
  __builtin_amdgcn_s_barrier();
  COMPUTE2(cur);
  if (++cur == 3) cur = 0;
  asm volatile("s_waitcnt vmcnt(0)" ::: "memory");
  __builtin_amdgcn_s_barrier();
  COMPUTE2(cur);

  const int q4 = (lane >> 4) * 4;
  const int c = lane & 15;
  float* yrow = ye + (size_t)kh * SLOTS_MAX * DM + (size_t)(hb + m0) * DM + n0;
#pragma unroll
  for (int i = 0; i < 8; i++) {
#pragma unroll
    for (int r = 0; r < 4; r++) {
      int m = wrow + i * 16 + q4 + r;
      if (m0 + m < cpad) {
#pragma unroll
        for (int j = 0; j < 4; j++) {
          int n = wcol + j * 16 + c;
          float v = acc[i][j][r];
          if (add_prev) v += yrow[(size_t)m * DM + n];
          yrow[(size_t)m * DM + n] = v;
        }
      }
    }
  }
#undef STAGE2
#undef COMPUTE2
}

// ------- gather: out[tok] = s0*(ye0+ye1+b2)[gs0] + s1*(ye0+ye1+b2)[gs1] --------
__global__ void gather_kernel(const float* __restrict__ ye,
                              const float* __restrict__ b2,
                              const int2* __restrict__ tope,
                              const float2* __restrict__ tops,
                              const int2* __restrict__ pos,
                              const int* __restrict__ base,
                              float* __restrict__ out) {
  int idx = blockIdx.x * 256 + threadIdx.x;
  int tok = idx / (DM / 4);
  int d4 = (idx % (DM / 4)) * 4;
  int2 e = tope[tok];
  float2 s = tops[tok];
  int2 p = pos[tok];
  const float* ye1 = ye + (size_t)SLOTS_MAX * DM;
  float4 r = make_float4(0.f, 0.f, 0.f, 0.f);
  if (p.x < CAP) {
    size_t row = (size_t)(base[e.x] + p.x) * DM + d4;
    const float4 va = *(const float4*)(ye + row);
    const float4 vb = *(const float4*)(ye1 + row);
    const float4 bb = *(const float4*)(b2 + e.x * DM + d4);
    r.x += s.x * (va.x + vb.x + bb.x); r.y += s.x * (va.y + vb.y + bb.y);
    r.z += s.x * (va.z + vb.z + bb.z); r.w += s.x * (va.w + vb.w + bb.w);
  }
  if (p.y < CAP) {
    size_t row = (size_t)(base[e.y] + p.y) * DM + d4;
    const float4 va = *(const float4*)(ye + row);
    const float4 vb = *(const float4*)(ye1 + row);
    const float4 bb = *(const float4*)(b2 + e.y * DM + d4);
    r.x += s.y * (va.x + vb.x + bb.x); r.y += s.y * (va.y + vb.y + bb.y);
    r.z += s.y * (va.z + vb.z + bb.z); r.w += s.y * (va.w + vb.w + bb.w);
  }
  *(float4*)(out + (size_t)tok * DM + d4) = r;
}

extern "C" void kernel_launch(void* const* d_in, const int* in_sizes, int n_in,
                              void* d_out, int out_size, void* d_ws, size_t ws_size,
                              hipStream_t stream) {
  const float* inp = (const float*)d_in[0];
  const float* gw  = (const float*)d_in[1];
  const float* gb  = (const float*)d_in[2];
  const float* w1  = (const float*)d_in[3];
  const float* b1  = (const float*)d_in[4];
  const float* w2  = (const float*)d_in[5];
  const float* b2  = (const float*)d_in[6];
  float* out = (float*)d_out;

  const size_t meta = 165376;
  // chunk selection: one SHARED transposed-weight buffer (w1t/w2t sequential).
  // chunk must be a multiple of 256 (transpose r-tiling, gemm2 A alignment).
  const int cands[6] = {3072, 1536, 1024, 768, 512, 256};
  int chunk = 256;
  for (int ci = 0; ci < 6; ci++) {
    int c = cands[ci];
    size_t need = meta + (size_t)NT * DM * 2                 // xb
                + (size_t)NE * c * DM * 2                    // shared wt
                + (size_t)SLOTS_MAX * c * 2                  // h
                + 2 * (size_t)SLOTS_MAX * DM * 4;            // ye (2 partials)
    if (need <= ws_size) { chunk = c; break; }
  }

  char* ws = (char*)d_ws;
  int*    cnt  = (int*)(ws);              // 256 B
  int*    base = (int*)(ws + 256);        // 256 B
  int*    srcb = (int*)(ws + 512);        // 64 KB  -> 66048
  int2*   tope = (int2*)(ws + 66048);     // 32 KB  -> 98816
  float2* tops = (float2*)(ws + 98816);   // 32 KB  -> 131584
  int2*   pos  = (int2*)(ws + 131584);    // 32 KB  -> 164352
  int2*   wl1  = (int2*)(ws + 164352);    // 576 B (72 entries)
  int2*   wl2  = (int2*)(ws + 164928);    // 320 B (40 entries)
  size_t off = meta;
  unsigned short* xb = (unsigned short*)(ws + off);  off += (size_t)NT * DM * 2;
  unsigned short* wt = (unsigned short*)(ws + off);  off += (size_t)NE * chunk * DM * 2;
  unsigned short* hc = (unsigned short*)(ws + off);  off += (size_t)SLOTS_MAX * chunk * 2;
  float* ye = (float*)(ws + off);

  convert_x_kernel<<<(NT * DM) / 1024, 256, 0, stream>>>(inp, xb);
  gate_dots_kernel<<<NT / 4, 256, 0, stream>>>(inp, gw, gb, tope, tops);
  assign_kernel<<<1, 1024, 0, stream>>>(tope, cnt, base, srcb, pos, wl1, wl2);

  for (int c = 0; c < HD; c += chunk) {
    // w1 chunk into shared wt: wt[e][h_local][d] = w1[e][d][c + h_local]
    transpose_kernel<<<NE * (chunk / 64) * (DM / 256), 256, 0, stream>>>(
        w1, wt, DM, HD, c, (size_t)DM * HD, (size_t)chunk * DM, chunk / 64);
    gemm1_kernel<<<(chunk / 128) * WDIM1, 256, 0, stream>>>(
        xb, wt, b1, cnt, base, srcb, wl1, hc, c, chunk);
    // w2 chunk into the SAME wt: wt[e][d][h_local] = w2[e][c + h_local][d]
    transpose_kernel<<<NE * (DM / 64) * (chunk / 256), 256, 0, stream>>>(
        w2 + (size_t)c * DM, wt, chunk, DM, 0, (size_t)HD * DM, (size_t)DM * chunk, DM / 64);
    gemm2_kernel<<<(2 * DM / 256) * WDIM2, 512, 0, stream>>>(
        hc, wt, cnt, base, wl2, ye, chunk, c == 0 ? 0 : 1);
  }

  gather_kernel<<<(NT * DM / 4) / 256, 256, 0, stream>>>(ye, b2, tope, tops, pos, base, out);
}

// Round 7
// 372.943 us; speedup vs baseline: 1.0973x; 1.0243x over previous
//
#include <hip/hip_runtime.h>
#include <hip/hip_bf16.h>
#include <math.h>

#define NT    4096
#define DM    768
#define HD    3072
#define NE    8
#define CAP   2048
// total compact rows: sum(roundup(min(cnt,CAP),128)) <= 8192 + 8*127 -> 9216
#define SLOTS_MAX 9216
// 128-row tile worklist (gemm1): <= 71 entries; 8 bins x 9 = 72
#define WDIM1 72
#define BINCAP1 9
// 256-row tile worklist (gemm2): <= 39 entries; 8 bins x 5 = 40
#define WDIM2 40
#define BINCAP2 5

typedef __attribute__((ext_vector_type(8))) short bf16x8;
typedef __attribute__((ext_vector_type(4))) float f32x4;

__device__ __forceinline__ unsigned short f2bf(float f) {
  unsigned int u = __float_as_uint(f);
  unsigned int r = (u + 0x7fffu + ((u >> 16) & 1u)) >> 16;
  return (unsigned short)r;
}

__device__ __forceinline__ void async16(const unsigned short* g, unsigned short* l) {
  __builtin_amdgcn_global_load_lds((const __attribute__((address_space(1))) void*)g,
                                   (__attribute__((address_space(3))) void*)l,
                                   16, 0, 0);
}

// ---- transpose+convert body: dst_bf16[e][c][r] = src_f32[e][r][coloff+c] ----
// 256 src-rows x 64 src-cols per tile. 256B-segment reads/writes; LDS packed
// row-pairs at stride 129 (<=2-way banks).
__device__ __forceinline__ void transpose_body(
    int idx, const float* __restrict__ src, unsigned short* __restrict__ dst,
    int R, int src_stride, int col_off,
    size_t src_e_stride, size_t dst_e_stride, int ncx,
    unsigned int* tile32) {
  const int e = idx & 7;
  const int rest = idx >> 3;
  const int c0 = (rest % ncx) * 64;
  const int r0 = (rest / ncx) * 256;
  const float* s = src + (size_t)e * src_e_stride + col_off;
  unsigned short* d = dst + (size_t)e * dst_e_stride;
  const int t = threadIdx.x;
  const int q16 = t & 15;
  const int tg = t >> 4;
#pragma unroll
  for (int i = 0; i < 8; i++) {
    int rl = tg * 2 + i * 32;
    const float4 f0 = *(const float4*)(s + (size_t)(r0 + rl) * src_stride + c0 + q16 * 4);
    const float4 f1 = *(const float4*)(s + (size_t)(r0 + rl + 1) * src_stride + c0 + q16 * 4);
    int j = tg + i * 16;
    tile32[(q16 * 4 + 0) * 129 + j] = (unsigned int)f2bf(f0.x) | ((unsigned int)f2bf(f1.x) << 16);
    tile32[(q16 * 4 + 1) * 129 + j] = (unsigned int)f2bf(f0.y) | ((unsigned int)f2bf(f1.y) << 16);
    tile32[(q16 * 4 + 2) * 129 + j] = (unsigned int)f2bf(f0.z) | ((unsigned int)f2bf(f1.z) << 16);
    tile32[(q16 * 4 + 3) * 129 + j] = (unsigned int)f2bf(f0.w) | ((unsigned int)f2bf(f1.w) << 16);
  }
  __syncthreads();
#pragma unroll
  for (int i = 0; i < 4; i++) {
    int cl = tg + i * 16;
    unsigned short* drow = d + (size_t)(c0 + cl) * R + r0;
#pragma unroll
    for (int half = 0; half < 2; half++) {
      int u = q16 * 4 + half * 64;
      uint4 v;
      v.x = tile32[cl * 129 + u + 0];
      v.y = tile32[cl * 129 + u + 1];
      v.z = tile32[cl * 129 + u + 2];
      v.w = tile32[cl * 129 + u + 3];
      *(uint4*)(drow + q16 * 8 + half * 128) = v;
    }
  }
}

// ---- fused prep: convert_x || gate || w1-transpose || w2-transpose ----------
// All four sections are mutually independent; one launch lets them share the
// memory system concurrently instead of serializing ~230MB of transpose
// traffic behind the tiny gate/convert kernels. Branch is per-BLOCK (safe
// barriers). nconv=3072, ngate=1024, nt1/nt2 = transpose tiles.
__global__ __launch_bounds__(256) void prep_kernel(
    const float* __restrict__ inp, unsigned short* __restrict__ xb,
    const float* __restrict__ gw, const float* __restrict__ gb,
    int2* __restrict__ tope, float2* __restrict__ tops,
    const float* __restrict__ w1, unsigned short* __restrict__ w1t,
    const float* __restrict__ w2, unsigned short* __restrict__ w2t,
    int chunk, int nconv, int ngate, int nt1, int nt2) {
  __shared__ unsigned int tile32[64 * 129];
  const int b = blockIdx.x;
  if (b < nconv) {
    // ---- convert x: fp32 -> bf16 ----
    int i = (b * 256 + threadIdx.x) * 4;
    float4 v = *(const float4*)(inp + i);
    uint2 o;
    o.x = (unsigned int)f2bf(v.x) | ((unsigned int)f2bf(v.y) << 16);
    o.y = (unsigned int)f2bf(v.z) | ((unsigned int)f2bf(v.w) << 16);
    *(uint2*)(xb + i) = o;
  } else if (b < nconv + ngate) {
    // ---- gate dots: logits, top-2, softmax ----
    const int tok  = (b - nconv) * 4 + (threadIdx.x >> 6);
    const int lane = threadIdx.x & 63;
    const float* x = inp + (size_t)tok * DM;
    float acc[NE];
#pragma unroll
    for (int e = 0; e < NE; e++) acc[e] = 0.f;
    for (int d = lane; d < DM; d += 64) {
      float xv = x[d];
      const float4 w0 = *(const float4*)(gw + d * NE);
      const float4 w1v = *(const float4*)(gw + d * NE + 4);
      acc[0] += xv * w0.x; acc[1] += xv * w0.y;
      acc[2] += xv * w0.z; acc[3] += xv * w0.w;
      acc[4] += xv * w1v.x; acc[5] += xv * w1v.y;
      acc[6] += xv * w1v.z; acc[7] += xv * w1v.w;
    }
#pragma unroll
    for (int e = 0; e < NE; e++) {
      float v = acc[e];
#pragma unroll
      for (int m = 32; m > 0; m >>= 1) v += __shfl_xor(v, m, 64);
      acc[e] = v + gb[e];
    }
    if (lane == 0) {
      float bv = -1e30f, sv = -1e30f; int bi = 0, si = 0;
#pragma unroll
      for (int e = 0; e < NE; e++) {
        float v = acc[e];
        if (v > bv)      { sv = bv; si = bi; bv = v; bi = e; }
        else if (v > sv) { sv = v;  si = e; }
      }
      float e1 = expf(sv - bv);
      tope[tok] = make_int2(bi, si);
      tops[tok] = make_float2(1.f / (1.f + e1), e1 / (1.f + e1));
    }
  } else if (b < nconv + ngate + nt1) {
    // ---- w1 chunk0: w1t[e][h_local][d] = w1[e][d][h_local] ----
    transpose_body(b - nconv - ngate, w1, w1t, DM, HD, 0,
                   (size_t)DM * HD, (size_t)chunk * DM, chunk / 64, tile32);
  } else {
    // ---- w2 chunk0: w2t[e][d][h_local] = w2[e][h_local][d] ----
    transpose_body(b - nconv - ngate - nt1, w2, w2t, chunk, DM, 0,
                   (size_t)HD * DM, (size_t)DM * chunk, DM / 64, tile32);
  }
}

// ---- fused both-transposes for chunk c > 0 (dual wt buffers) ----------------
__global__ __launch_bounds__(256) void transpose_both_kernel(
    const float* __restrict__ w1, unsigned short* __restrict__ w1t,
    const float* __restrict__ w2, unsigned short* __restrict__ w2t,
    int chunk, int c, int nt1) {
  __shared__ unsigned int tile32[64 * 129];
  const int b = blockIdx.x;
  if (b < nt1) {
    transpose_body(b, w1, w1t, DM, HD, c,
                   (size_t)DM * HD, (size_t)chunk * DM, chunk / 64, tile32);
  } else {
    transpose_body(b - nt1, w2 + (size_t)c * DM, w2t, chunk, DM, 0,
                   (size_t)HD * DM, (size_t)DM * chunk, DM / 64, tile32);
  }
}

// -------- assign: slot positions, ballot-aggregated LDS atomics ----------------
__device__ __forceinline__ int agg_inc(int* lcnt, int key) {
  const int lane = threadIdx.x & 63;
  int p = 0;
#pragma unroll
  for (int ee = 0; ee < NE; ee++) {
    unsigned long long m = __ballot(key == ee);
    if (m) {
      int leader = __ffsll(m) - 1;
      int n = __popcll(m);
      int b = 0;
      if (lane == leader) b = atomicAdd(&lcnt[ee], n);
      b = __shfl(b, leader, 64);
      if (key == ee) p = b + __popcll(m & ((1ull << lane) - 1ull));
    }
  }
  return p;
}

__global__ void assign_kernel(const int2* __restrict__ tope,
                              int* __restrict__ cnt,
                              int* __restrict__ base,
                              int* __restrict__ src,
                              int2* __restrict__ pos,
                              int2* __restrict__ wl1,
                              int2* __restrict__ wl2) {
  __shared__ int lcnt[NE];
  const int t = threadIdx.x;
  if (t < NE) lcnt[t] = 0;
  __syncthreads();
  for (int i = t; i < NT; i += 1024) {
    int2 e = tope[i];
    int p0 = agg_inc(lcnt, e.x);
    int p1 = agg_inc(lcnt, e.y);
    if (p0 < CAP) src[e.x * CAP + p0] = i;
    if (p1 < CAP) src[e.y * CAP + p1] = i;
    pos[i] = make_int2(p0, p1);
  }
  __syncthreads();
  if (t == 0) {
    int b = 0;
    for (int e = 0; e < NE; e++) {
      int c = min(lcnt[e], CAP);
      cnt[e] = c;
      base[e] = b;
      b += (c + 127) & ~127;
    }
    // Balanced-affinity worklists: fill 8 XCD bins in expert order -> each bin
    // holds tiles of 1-2 experts (B-panel L2 affinity) with balanced makespan.
    // wl[slot*8 + bin]; XCD = blockIdx%8 = wi%8 = bin.
    for (int s = 0; s < WDIM1; s++) wl1[s] = make_int2(-1, 0);
    int bin = 0, fill = 0;
    for (int e = 0; e < NE; e++) {
      int ntl = (cnt[e] + 127) >> 7;
      for (int mt = 0; mt < ntl; mt++) {
        if (fill == BINCAP1) { bin++; fill = 0; }
        wl1[fill * 8 + bin] = make_int2(e, mt * 128);
        fill++;
      }
    }
    for (int s = 0; s < WDIM2; s++) wl2[s] = make_int2(-1, 0);
    bin = 0; fill = 0;
    for (int e = 0; e < NE; e++) {
      int ntl = (cnt[e] + 255) >> 8;
      for (int mt = 0; mt < ntl; mt++) {
        if (fill == BINCAP2) { bin++; fill = 0; }
        wl2[fill * 8 + bin] = make_int2(e, mt * 256);
        fill++;
      }
    }
  }
}

// ---------------- GEMM1: h_c = gelu(gather(xb) @ w1_chunk + b1) ---------------
// 128x128x32, 256 thr, 48KB 3-buf LDS, depth-2 counted vmcnt, kc XOR-swizzle,
// LDS-staged coalesced epilogue (128B hc segments).
__global__ __launch_bounds__(256) void gemm1_kernel(
    const unsigned short* __restrict__ xb,    // [NT][DM] bf16
    const unsigned short* __restrict__ w1t,   // [E][chunk][DM] bf16
    const float* __restrict__ b1,             // [E][HD] fp32
    const int* __restrict__ cnt,
    const int* __restrict__ base,
    const int* __restrict__ src,
    const int2* __restrict__ wl,
    unsigned short* __restrict__ h,           // [SLOTS_MAX][chunk] bf16
    int hoff, int chunk) {
  const int b = blockIdx.x;
  const int wi = b % WDIM1;
  const int nt = b / WDIM1;
  const int2 wle = wl[wi];
  if (wle.x < 0) return;
  const int e = wle.x;
  const int m0 = wle.y;
  const int n0 = nt * 128;
  const int count = cnt[e];
  const int hb = base[e];

  __shared__ unsigned short As[3 * 4096];   // 3 x [128][32]
  __shared__ unsigned short Bs[3 * 4096];

  const int t = threadIdx.x;
  const int lane = t & 63;
  const int wave = t >> 6;
  const int r0 = t >> 2;
  // swizzled staging k-group: g_data = g_phys ^ ((row>>1)&3)
  const int kc = ((t & 3) ^ ((t >> 3) & 3)) * 8;

  const int tok0 = (m0 + r0      < count) ? src[e * CAP + m0 + r0]      : 0;
  const int tok1 = (m0 + r0 + 64 < count) ? src[e * CAP + m0 + r0 + 64] : 0;
  const unsigned short* aptr0 = xb + (size_t)tok0 * DM + kc;
  const unsigned short* aptr1 = xb + (size_t)tok1 * DM + kc;
  const unsigned short* w1e = w1t + (size_t)e * chunk * DM;
  const unsigned short* bptr0 = w1e + (size_t)(n0 + r0) * DM + kc;
  const unsigned short* bptr1 = bptr0 + (size_t)64 * DM;

  const int wrow = (wave >> 1) * 64;
  const int wcol = (wave & 1) * 64;
  const int lrow = lane & 15;
  // swizzled read k-offset (matches staging permutation; conflict-free)
  const int koff = ((lane >> 4) ^ ((lane >> 1) & 3)) * 8;

  f32x4 acc[4][4];
#pragma unroll
  for (int i = 0; i < 4; i++)
#pragma unroll
    for (int j = 0; j < 4; j++) acc[i][j] = (f32x4){0.f, 0.f, 0.f, 0.f};

#define STAGE1(bi, kk) do {                                   \
    unsigned short* A_ = As + (bi) * 4096 + wave * 512;       \
    unsigned short* B_ = Bs + (bi) * 4096 + wave * 512;       \
    async16(aptr0 + (kk), A_);                                \
    async16(aptr1 + (kk), A_ + 2048);                         \
    async16(bptr0 + (kk), B_);                                \
    async16(bptr1 + (kk), B_ + 2048);                         \
  } while (0)

#define COMPUTE1(bi) do {                                               \
    const unsigned short* A_ = As + (bi) * 4096;                        \
    const unsigned short* B_ = Bs + (bi) * 4096;                        \
    bf16x8 af[4], bfr[4];                                               \
    _Pragma("unroll")                                                   \
    for (int i = 0; i < 4; i++)                                         \
      af[i] = *(const bf16x8*)(A_ + (wrow + i * 16 + lrow) * 32 + koff);\
    _Pragma("unroll")                                                   \
    for (int j = 0; j < 4; j++)                                         \
      bfr[j] = *(const bf16x8*)(B_ + (wcol + j * 16 + lrow) * 32 + koff);\
    _Pragma("unroll")                                                   \
    for (int i = 0; i < 4; i++)                                         \
      _Pragma("unroll")                                                 \
      for (int j = 0; j < 4; j++)                                       \
        acc[i][j] = __builtin_amdgcn_mfma_f32_16x16x32_bf16(af[i], bfr[j], acc[i][j], 0, 0, 0); \
  } while (0)

  const int NS = DM / 32;   // 24 K-steps
  STAGE1(0, 0);
  STAGE1(1, 32);
  int cur = 0;
  for (int ts = 0; ts < NS - 2; ++ts) {
    int pf = cur + 2; if (pf >= 3) pf -= 3;
    STAGE1(pf, (ts + 2) * 32);
    asm volatile("s_waitcnt vmcnt(8)" ::: "memory");   // tile ts landed (own 4 oldest)
    __builtin_amdgcn_s_barrier();                       // landed for ALL waves
    COMPUTE1(cur);
    asm volatile("s_waitcnt lgkmcnt(0)" ::: "memory"); // reads retired before free
    __builtin_amdgcn_s_barrier();                       // buffer free for overwrite
    if (++cur == 3) cur = 0;
  }
  asm volatile("s_waitcnt vmcnt(4)" ::: "memory");
  __builtin_amdgcn_s_barrier();
  COMPUTE1(cur);
  if (++cur == 3) cur = 0;
  asm volatile("s_waitcnt vmcnt(0)" ::: "memory");
  __builtin_amdgcn_s_barrier();
  COMPUTE1(cur);

  // ---- epilogue: gelu + LDS-staged coalesced store (128B segments) ----
  __syncthreads();   // all waves done reading As/Bs; safe to reuse as C slab
  const int q4 = (lane >> 4) * 4;
  const int c = lane & 15;
  // per-wave slab: 64 rows x 72 shorts (144B rows -> 16B aligned reads)
  unsigned short* slab = (wave < 2) ? (As + wave * 4608) : (Bs + (wave - 2) * 4608);
#pragma unroll
  for (int j = 0; j < 4; j++) {
    const float bias = b1[e * HD + hoff + n0 + wcol + j * 16 + c];
#pragma unroll
    for (int i = 0; i < 4; i++) {
#pragma unroll
      for (int r = 0; r < 4; r++) {
        float v = acc[i][j][r] + bias;
        // exact identity: 0.5*v*(1+tanh(u)) == v * sigmoid(2u)
        float u2 = 1.5957691216f * (v + 0.044715f * v * v * v);
        float g = v / (1.f + __expf(-u2));
        slab[(i * 16 + q4 + r) * 72 + j * 16 + c] = f2bf(g);
      }
    }
  }
  asm volatile("s_waitcnt lgkmcnt(0)" ::: "memory");  // own writes visible (own slab only)
  const int l8 = lane & 7;
  const int r8 = lane >> 3;
  unsigned short* hrow = h + (size_t)(hb + m0 + wrow) * chunk + n0 + wcol;
#pragma unroll
  for (int p = 0; p < 8; p++) {
    int lm = p * 8 + r8;
    uint4 v = *(const uint4*)(slab + lm * 72 + l8 * 8);
    *(uint4*)(hrow + (size_t)lm * chunk + l8 * 8) = v;
  }
#undef STAGE1
#undef COMPUTE1
}

// -------- GEMM2 split-K: ye_part[kh][slot] = h_half @ w2_half (+ prev) ---------
// 256x256x32 tiles, 512 thr (8 waves 2Mx4N), 96KB 3-buf LDS, depth-2 counted
// vmcnt, kc XOR-swizzle. b = fast*WDIM2 + wi, fast = kh*3 + n-tile; XCD = wi%8.
__global__ __launch_bounds__(512) void gemm2_kernel(
    const unsigned short* __restrict__ h,     // [SLOTS_MAX][chunk] bf16
    const unsigned short* __restrict__ w2t,   // [E][DM][chunk] bf16
    const int* __restrict__ cnt,
    const int* __restrict__ base,
    const int2* __restrict__ wl,
    float* __restrict__ ye,                   // [2][SLOTS_MAX][DM] fp32
    int chunk, int add_prev) {
  const int b = blockIdx.x;
  const int wi = b % WDIM2;
  const int fast = b / WDIM2;            // 0..5
  const int2 wle = wl[wi];
  if (wle.x < 0) return;
  const int e = wle.x;
  const int m0 = wle.y;
  const int kh = fast / 3;
  const int n0 = (fast % 3) * 256;
  const int count = cnt[e];
  const int cpad = (count + 127) & ~127;
  const int hb = base[e];
  const int khalf = chunk >> 1;

  __shared__ unsigned short As[3 * 8192];
  __shared__ unsigned short Bs[3 * 8192];

  const int t = threadIdx.x;
  const int lane = t & 63;
  const int wave = t >> 6;
  const int r0 = t >> 2;
  const int kc = ((t & 3) ^ ((t >> 3) & 3)) * 8;

  const unsigned short* aptr0 = h + (size_t)(hb + m0 + r0) * chunk + kh * khalf + kc;
  const unsigned short* aptr1 = aptr0 + (size_t)128 * chunk;
  const unsigned short* w2e = w2t + (size_t)e * DM * chunk;
  const unsigned short* bptr0 = w2e + (size_t)(n0 + r0) * chunk + kh * khalf + kc;
  const unsigned short* bptr1 = bptr0 + (size_t)128 * chunk;

  const int wrow = (wave >> 2) * 128;
  const int wcol = (wave & 3) * 64;
  const int lrow = lane & 15;
  const int koff = ((lane >> 4) ^ ((lane >> 1) & 3)) * 8;

  f32x4 acc[8][4];
#pragma unroll
  for (int i = 0; i < 8; i++)
#pragma unroll
    for (int j = 0; j < 4; j++) acc[i][j] = (f32x4){0.f, 0.f, 0.f, 0.f};

#define STAGE2(bi, kk) do {                                   \
    unsigned short* A_ = As + (bi) * 8192 + wave * 512;       \
    unsigned short* B_ = Bs + (bi) * 8192 + wave * 512;       \
    async16(aptr0 + (kk), A_);                                \
    async16(aptr1 + (kk), A_ + 4096);                         \
    async16(bptr0 + (kk), B_);                                \
    async16(bptr1 + (kk), B_ + 4096);                         \
  } while (0)

#define COMPUTE2(bi) do {                                               \
    const unsigned short* A_ = As + (bi) * 8192;                        \
    const unsigned short* B_ = Bs + (bi) * 8192;                        \
    bf16x8 af[8], bfr[4];                                               \
    _Pragma("unroll")                                                   \
    for (int i = 0; i < 8; i++)                                         \
      af[i] = *(const bf16x8*)(A_ + (wrow + i * 16 + lrow) * 32 + koff);\
    _Pragma("unroll")                                                   \
    for (int j = 0; j < 4; j++)                                         \
      bfr[j] = *(const bf16x8*)(B_ + (wcol + j * 16 + lrow) * 32 + koff);\
    _Pragma("unroll")                                                   \
    for (int i = 0; i < 8; i++)                                         \
      _Pragma("unroll")                                                 \
      for (int j = 0; j < 4; j++)                                       \
        acc[i][j] = __builtin_amdgcn_mfma_f32_16x16x32_bf16(af[i], bfr[j], acc[i][j], 0, 0, 0); \
  } while (0)

  const int NS = khalf >> 5;            // 48 for chunk=3072
  STAGE2(0, 0);
  STAGE2(1, 32);
  int cur = 0;
  for (int ts = 0; ts < NS - 2; ++ts) {
    int pf = cur + 2; if (pf >= 3) pf -= 3;
    STAGE2(pf, (ts + 2) * 32);
    asm volatile("s_waitcnt vmcnt(8)" ::: "memory");
    __builtin_amdgcn_s_barrier();
    COMPUTE2(cur);
    asm volatile("s_waitcnt lgkmcnt(0)" ::: "memory");
    __builtin_amdgcn_s_barrier();
    if (++cur == 3) cur = 0;
  }
  asm volatile("s_waitcnt vmcnt(4)" ::: "memory");
  __builtin_amdgcn_s_barrier();
  COMPUTE2(cur);
  if (++cur == 3) cur = 0;
  asm volatile("s_waitcnt vmcnt(0)" ::: "memory");
  __builtin_amdgcn_s_barrier();
  COMPUTE2(cur);

  const int q4 = (lane >> 4) * 4;
  const int c = lane & 15;
  float* yrow = ye + (size_t)kh * SLOTS_MAX * DM + (size_t)(hb + m0) * DM + n0;
#pragma unroll
  for (int i = 0; i < 8; i++) {
#pragma unroll
    for (int r = 0; r < 4; r++) {
      int m = wrow + i * 16 + q4 + r;
      if (m0 + m < cpad) {
#pragma unroll
        for (int j = 0; j < 4; j++) {
          int n = wcol + j * 16 + c;
          float v = acc[i][j][r];
          if (add_prev) v += yrow[(size_t)m * DM + n];
          yrow[(size_t)m * DM + n] = v;
        }
      }
    }
  }
#undef STAGE2
#undef COMPUTE2
}

// ------- gather: out[tok] = s0*(ye0+ye1+b2)[gs0] + s1*(ye0+ye1+b2)[gs1] --------
__global__ void gather_kernel(const float* __restrict__ ye,
                              const float* __restrict__ b2,
                              const int2* __restrict__ tope,
                              const float2* __restrict__ tops,
                              const int2* __restrict__ pos,
                              const int* __restrict__ base,
                              float* __restrict__ out) {
  int idx = blockIdx.x * 256 + threadIdx.x;
  int tok = idx / (DM / 4);
  int d4 = (idx % (DM / 4)) * 4;
  int2 e = tope[tok];
  float2 s = tops[tok];
  int2 p = pos[tok];
  const float* ye1 = ye + (size_t)SLOTS_MAX * DM;
  float4 r = make_float4(0.f, 0.f, 0.f, 0.f);
  if (p.x < CAP) {
    size_t row = (size_t)(base[e.x] + p.x) * DM + d4;
    const float4 va = *(const float4*)(ye + row);
    const float4 vb = *(const float4*)(ye1 + row);
    const float4 bb = *(const float4*)(b2 + e.x * DM + d4);
    r.x += s.x * (va.x + vb.x + bb.x); r.y += s.x * (va.y + vb.y + bb.y);
    r.z += s.x * (va.z + vb.z + bb.z); r.w += s.x * (va.w + vb.w + bb.w);
  }
  if (p.y < CAP) {
    size_t row = (size_t)(base[e.y] + p.y) * DM + d4;
    const float4 va = *(const float4*)(ye + row);
    const float4 vb = *(const float4*)(ye1 + row);
    const float4 bb = *(const float4*)(b2 + e.y * DM + d4);
    r.x += s.y * (va.x + vb.x + bb.x); r.y += s.y * (va.y + vb.y + bb.y);
    r.z += s.y * (va.z + vb.z + bb.z); r.w += s.y * (va.w + vb.w + bb.w);
  }
  *(float4*)(out + (size_t)tok * DM + d4) = r;
}

extern "C" void kernel_launch(void* const* d_in, const int* in_sizes, int n_in,
                              void* d_out, int out_size, void* d_ws, size_t ws_size,
                              hipStream_t stream) {
  const float* inp = (const float*)d_in[0];
  const float* gw  = (const float*)d_in[1];
  const float* gb  = (const float*)d_in[2];
  const float* w1  = (const float*)d_in[3];
  const float* b1  = (const float*)d_in[4];
  const float* w2  = (const float*)d_in[5];
  const float* b2  = (const float*)d_in[6];
  float* out = (float*)d_out;

  const size_t meta = 165376;
  // chunk selection with DUAL wt buffers (w1t and w2t live simultaneously so
  // both transposes can run inside one fused kernel). chunk mult of 256.
  const int cands[6] = {3072, 1536, 1024, 768, 512, 256};
  int chunk = 256;
  for (int ci = 0; ci < 6; ci++) {
    int c = cands[ci];
    size_t need = meta + (size_t)NT * DM * 2                 // xb
                + 2 * (size_t)NE * c * DM * 2                // w1t + w2t
                + (size_t)SLOTS_MAX * c * 2                  // h
                + 2 * (size_t)SLOTS_MAX * DM * 4;            // ye (2 partials)
    if (need <= ws_size) { chunk = c; break; }
  }

  char* ws = (char*)d_ws;
  int*    cnt  = (int*)(ws);              // 256 B
  int*    base = (int*)(ws + 256);        // 256 B
  int*    srcb = (int*)(ws + 512);        // 64 KB  -> 66048
  int2*   tope = (int2*)(ws + 66048);     // 32 KB  -> 98816
  float2* tops = (float2*)(ws + 98816);   // 32 KB  -> 131584
  int2*   pos  = (int2*)(ws + 131584);    // 32 KB  -> 164352
  int2*   wl1  = (int2*)(ws + 164352);    // 576 B (72 entries)
  int2*   wl2  = (int2*)(ws + 164928);    // 320 B (40 entries)
  size_t off = meta;
  unsigned short* xb  = (unsigned short*)(ws + off);  off += (size_t)NT * DM * 2;
  unsigned short* w1t = (unsigned short*)(ws + off);  off += (size_t)NE * chunk * DM * 2;
  unsigned short* w2t = (unsigned short*)(ws + off);  off += (size_t)NE * chunk * DM * 2;
  unsigned short* hc  = (unsigned short*)(ws + off);  off += (size_t)SLOTS_MAX * chunk * 2;
  float* ye = (float*)(ws + off);

  const int nconv = (NT * DM) / 1024;                       // 3072
  const int ngate = NT / 4;                                 // 1024
  const int nt1 = NE * (chunk / 64) * (DM / 256);           // w1 tiles
  const int nt2 = NE * (DM / 64) * (chunk / 256);           // w2 tiles

  // fused front-end: convert || gate || w1-transpose(c0) || w2-transpose(c0)
  prep_kernel<<<nconv + ngate + nt1 + nt2, 256, 0, stream>>>(
      inp, xb, gw, gb, tope, tops, w1, w1t, w2, w2t,
      chunk, nconv, ngate, nt1, nt2);
  assign_kernel<<<1, 1024, 0, stream>>>(tope, cnt, base, srcb, pos, wl1, wl2);

  for (int c = 0; c < HD; c += chunk) {
    if (c > 0)
      transpose_both_kernel<<<nt1 + nt2, 256, 0, stream>>>(
          w1, w1t, w2, w2t, chunk, c, nt1);
    gemm1_kernel<<<(chunk / 128) * WDIM1, 256, 0, stream>>>(
        xb, w1t, b1, cnt, base, srcb, wl1, hc, c, chunk);
    gemm2_kernel<<<(2 * DM / 256) * WDIM2, 512, 0, stream>>>(
        hc, w2t, cnt, base, wl2, ye, chunk, c == 0 ? 0 : 1);
  }

  gather_kernel<<<(NT * DM / 4) / 256, 256, 0, stream>>>(ye, b2, tope, tops, pos, base, out);
}

// Round 8
// 371.154 us; speedup vs baseline: 1.1026x; 1.0048x over previous
//
#include <hip/hip_runtime.h>
#include <hip/hip_bf16.h>
#include <math.h>

#define NT    4096
#define DM    768
#define HD    3072
#define NE    8
#define CAP   2048
// total compact rows: sum(roundup(min(cnt,CAP),128)) <= 8192 + 8*127 -> 9216
#define SLOTS_MAX 9216
// 128-row tile worklist (gemm1): <= 71 entries; 8 bins x 9 = 72
#define WDIM1 72
#define BINCAP1 9
// 256-row tile worklist (gemm2): <= 39 entries; 8 bins x 5 = 40
#define WDIM2 40
#define BINCAP2 5

typedef __attribute__((ext_vector_type(8))) short bf16x8;
typedef __attribute__((ext_vector_type(4))) float f32x4;

__device__ __forceinline__ unsigned short f2bf(float f) {
  unsigned int u = __float_as_uint(f);
  unsigned int r = (u + 0x7fffu + ((u >> 16) & 1u)) >> 16;
  return (unsigned short)r;
}

__device__ __forceinline__ void async16(const unsigned short* g, unsigned short* l) {
  __builtin_amdgcn_global_load_lds((const __attribute__((address_space(1))) void*)g,
                                   (__attribute__((address_space(3))) void*)l,
                                   16, 0, 0);
}

// ---- transpose+convert body: dst_bf16[e][c][r] = src_f32[e][r][coloff+c] ----
// 256 src-rows x 64 src-cols per tile. ILP-restructured: 8 float4 loads are
// issued into registers BEFORE any convert/LDS write (two half-passes), so
// ~8 loads/thread stay in flight (prev: ~2 -> latency-bound at 2.8 TB/s).
__device__ __forceinline__ void transpose_body(
    int idx, const float* __restrict__ src, unsigned short* __restrict__ dst,
    int R, int src_stride, int col_off,
    size_t src_e_stride, size_t dst_e_stride, int ncx,
    unsigned int* tile32) {
  const int e = idx & 7;
  const int rest = idx >> 3;
  const int c0 = (rest % ncx) * 64;
  const int r0 = (rest / ncx) * 256;
  const float* s = src + (size_t)e * src_e_stride + col_off;
  unsigned short* d = dst + (size_t)e * dst_e_stride;
  const int t = threadIdx.x;
  const int q16 = t & 15;
  const int tg = t >> 4;
#pragma unroll
  for (int half8 = 0; half8 < 2; half8++) {
    float4 f0[4], f1[4];
#pragma unroll
    for (int i = 0; i < 4; i++) {
      int rl = tg * 2 + (half8 * 4 + i) * 32;
      f0[i] = *(const float4*)(s + (size_t)(r0 + rl) * src_stride + c0 + q16 * 4);
      f1[i] = *(const float4*)(s + (size_t)(r0 + rl + 1) * src_stride + c0 + q16 * 4);
    }
#pragma unroll
    for (int i = 0; i < 4; i++) {
      int j = tg + (half8 * 4 + i) * 16;
      tile32[(q16 * 4 + 0) * 129 + j] = (unsigned int)f2bf(f0[i].x) | ((unsigned int)f2bf(f1[i].x) << 16);
      tile32[(q16 * 4 + 1) * 129 + j] = (unsigned int)f2bf(f0[i].y) | ((unsigned int)f2bf(f1[i].y) << 16);
      tile32[(q16 * 4 + 2) * 129 + j] = (unsigned int)f2bf(f0[i].z) | ((unsigned int)f2bf(f1[i].z) << 16);
      tile32[(q16 * 4 + 3) * 129 + j] = (unsigned int)f2bf(f0[i].w) | ((unsigned int)f2bf(f1[i].w) << 16);
    }
  }
  __syncthreads();
#pragma unroll
  for (int i = 0; i < 4; i++) {
    int cl = tg + i * 16;
    unsigned short* drow = d + (size_t)(c0 + cl) * R + r0;
#pragma unroll
    for (int half = 0; half < 2; half++) {
      int u = q16 * 4 + half * 64;
      uint4 v;
      v.x = tile32[cl * 129 + u + 0];
      v.y = tile32[cl * 129 + u + 1];
      v.z = tile32[cl * 129 + u + 2];
      v.w = tile32[cl * 129 + u + 3];
      *(uint4*)(drow + q16 * 8 + half * 128) = v;
    }
  }
}

// ---- fused prep: (gate + x-convert) || w1-transpose || w2-transpose ---------
// Gate section now also emits xb (it reads every x element anyway) -> the
// separate convert pass and its 12.6MB inp re-read are gone.
__global__ __launch_bounds__(256, 4) void prep_kernel(
    const float* __restrict__ inp, unsigned short* __restrict__ xb,
    const float* __restrict__ gw, const float* __restrict__ gb,
    int2* __restrict__ tope, float2* __restrict__ tops,
    const float* __restrict__ w1, unsigned short* __restrict__ w1t,
    const float* __restrict__ w2, unsigned short* __restrict__ w2t,
    int chunk, int ngate, int nt1) {
  __shared__ unsigned int tile32[64 * 129];
  const int b = blockIdx.x;
  if (b < ngate) {
    // ---- gate dots + bf16 convert: 4 tokens/block ----
    const int tok  = b * 4 + (threadIdx.x >> 6);
    const int lane = threadIdx.x & 63;
    const float* x = inp + (size_t)tok * DM;
    unsigned short* xrow = xb + (size_t)tok * DM;
    float acc[NE];
#pragma unroll
    for (int e = 0; e < NE; e++) acc[e] = 0.f;
#pragma unroll
    for (int i = 0; i < 3; i++) {
      const int d0 = (i * 64 + lane) * 4;
      const float4 xv = *(const float4*)(x + d0);
      uint2 o;
      o.x = (unsigned int)f2bf(xv.x) | ((unsigned int)f2bf(xv.y) << 16);
      o.y = (unsigned int)f2bf(xv.z) | ((unsigned int)f2bf(xv.w) << 16);
      *(uint2*)(xrow + d0) = o;
#pragma unroll
      for (int j = 0; j < 4; j++) {
        const float xs = (j == 0) ? xv.x : (j == 1) ? xv.y : (j == 2) ? xv.z : xv.w;
        const float4 w0 = *(const float4*)(gw + (d0 + j) * NE);
        const float4 w1v = *(const float4*)(gw + (d0 + j) * NE + 4);
        acc[0] += xs * w0.x; acc[1] += xs * w0.y;
        acc[2] += xs * w0.z; acc[3] += xs * w0.w;
        acc[4] += xs * w1v.x; acc[5] += xs * w1v.y;
        acc[6] += xs * w1v.z; acc[7] += xs * w1v.w;
      }
    }
#pragma unroll
    for (int e = 0; e < NE; e++) {
      float v = acc[e];
#pragma unroll
      for (int m = 32; m > 0; m >>= 1) v += __shfl_xor(v, m, 64);
      acc[e] = v + gb[e];
    }
    if (lane == 0) {
      float bv = -1e30f, sv = -1e30f; int bi = 0, si = 0;
#pragma unroll
      for (int e = 0; e < NE; e++) {
        float v = acc[e];
        if (v > bv)      { sv = bv; si = bi; bv = v; bi = e; }
        else if (v > sv) { sv = v;  si = e; }
      }
      float e1 = expf(sv - bv);
      tope[tok] = make_int2(bi, si);
      tops[tok] = make_float2(1.f / (1.f + e1), e1 / (1.f + e1));
    }
  } else if (b < ngate + nt1) {
    // ---- w1 chunk0: w1t[e][h_local][d] = w1[e][d][h_local] ----
    transpose_body(b - ngate, w1, w1t, DM, HD, 0,
                   (size_t)DM * HD, (size_t)chunk * DM, chunk / 64, tile32);
  } else {
    // ---- w2 chunk0: w2t[e][d][h_local] = w2[e][h_local][d] ----
    transpose_body(b - ngate - nt1, w2, w2t, chunk, DM, 0,
                   (size_t)HD * DM, (size_t)DM * chunk, DM / 64, tile32);
  }
}

// ---- fused both-transposes for chunk c > 0 (dual wt buffers) ----------------
__global__ __launch_bounds__(256, 4) void transpose_both_kernel(
    const float* __restrict__ w1, unsigned short* __restrict__ w1t,
    const float* __restrict__ w2, unsigned short* __restrict__ w2t,
    int chunk, int c, int nt1) {
  __shared__ unsigned int tile32[64 * 129];
  const int b = blockIdx.x;
  if (b < nt1) {
    transpose_body(b, w1, w1t, DM, HD, c,
                   (size_t)DM * HD, (size_t)chunk * DM, chunk / 64, tile32);
  } else {
    transpose_body(b - nt1, w2 + (size_t)c * DM, w2t, chunk, DM, 0,
                   (size_t)HD * DM, (size_t)DM * chunk, DM / 64, tile32);
  }
}

// -------- assign: slot positions, ballot-aggregated LDS atomics ----------------
__device__ __forceinline__ int agg_inc(int* lcnt, int key) {
  const int lane = threadIdx.x & 63;
  int p = 0;
#pragma unroll
  for (int ee = 0; ee < NE; ee++) {
    unsigned long long m = __ballot(key == ee);
    if (m) {
      int leader = __ffsll(m) - 1;
      int n = __popcll(m);
      int b = 0;
      if (lane == leader) b = atomicAdd(&lcnt[ee], n);
      b = __shfl(b, leader, 64);
      if (key == ee) p = b + __popcll(m & ((1ull << lane) - 1ull));
    }
  }
  return p;
}

__global__ void assign_kernel(const int2* __restrict__ tope,
                              int* __restrict__ cnt,
                              int* __restrict__ base,
                              int* __restrict__ src,
                              int2* __restrict__ pos,
                              int2* __restrict__ wl1,
                              int2* __restrict__ wl2) {
  __shared__ int lcnt[NE];
  const int t = threadIdx.x;
  if (t < NE) lcnt[t] = 0;
  __syncthreads();
  for (int i = t; i < NT; i += 1024) {
    int2 e = tope[i];
    int p0 = agg_inc(lcnt, e.x);
    int p1 = agg_inc(lcnt, e.y);
    if (p0 < CAP) src[e.x * CAP + p0] = i;
    if (p1 < CAP) src[e.y * CAP + p1] = i;
    pos[i] = make_int2(p0, p1);
  }
  __syncthreads();
  if (t == 0) {
    int b = 0;
    for (int e = 0; e < NE; e++) {
      int c = min(lcnt[e], CAP);
      cnt[e] = c;
      base[e] = b;
      b += (c + 127) & ~127;
    }
    // Balanced-affinity worklists: fill 8 XCD bins in expert order -> each bin
    // holds tiles of 1-2 experts (B-panel L2 affinity) with balanced makespan.
    // wl[slot*8 + bin]; XCD = blockIdx%8 = wi%8 = bin.
    for (int s = 0; s < WDIM1; s++) wl1[s] = make_int2(-1, 0);
    int bin = 0, fill = 0;
    for (int e = 0; e < NE; e++) {
      int ntl = (cnt[e] + 127) >> 7;
      for (int mt = 0; mt < ntl; mt++) {
        if (fill == BINCAP1) { bin++; fill = 0; }
        wl1[fill * 8 + bin] = make_int2(e, mt * 128);
        fill++;
      }
    }
    for (int s = 0; s < WDIM2; s++) wl2[s] = make_int2(-1, 0);
    bin = 0; fill = 0;
    for (int e = 0; e < NE; e++) {
      int ntl = (cnt[e] + 255) >> 8;
      for (int mt = 0; mt < ntl; mt++) {
        if (fill == BINCAP2) { bin++; fill = 0; }
        wl2[fill * 8 + bin] = make_int2(e, mt * 256);
        fill++;
      }
    }
  }
}

// ---------------- GEMM1: h_c = gelu(gather(xb) @ w1_chunk + b1) ---------------
// 128x128x32, 256 thr, 48KB 3-buf LDS, depth-2 counted vmcnt, kc XOR-swizzle,
// LDS-staged coalesced epilogue (128B hc segments).
__global__ __launch_bounds__(256) void gemm1_kernel(
    const unsigned short* __restrict__ xb,    // [NT][DM] bf16
    const unsigned short* __restrict__ w1t,   // [E][chunk][DM] bf16
    const float* __restrict__ b1,             // [E][HD] fp32
    const int* __restrict__ cnt,
    const int* __restrict__ base,
    const int* __restrict__ src,
    const int2* __restrict__ wl,
    unsigned short* __restrict__ h,           // [SLOTS_MAX][chunk] bf16
    int hoff, int chunk) {
  const int b = blockIdx.x;
  const int wi = b % WDIM1;
  const int nt = b / WDIM1;
  const int2 wle = wl[wi];
  if (wle.x < 0) return;
  const int e = wle.x;
  const int m0 = wle.y;
  const int n0 = nt * 128;
  const int count = cnt[e];
  const int hb = base[e];

  __shared__ unsigned short As[3 * 4096];   // 3 x [128][32]
  __shared__ unsigned short Bs[3 * 4096];

  const int t = threadIdx.x;
  const int lane = t & 63;
  const int wave = t >> 6;
  const int r0 = t >> 2;
  // swizzled staging k-group: g_data = g_phys ^ ((row>>1)&3)
  const int kc = ((t & 3) ^ ((t >> 3) & 3)) * 8;

  const int tok0 = (m0 + r0      < count) ? src[e * CAP + m0 + r0]      : 0;
  const int tok1 = (m0 + r0 + 64 < count) ? src[e * CAP + m0 + r0 + 64] : 0;
  const unsigned short* aptr0 = xb + (size_t)tok0 * DM + kc;
  const unsigned short* aptr1 = xb + (size_t)tok1 * DM + kc;
  const unsigned short* w1e = w1t + (size_t)e * chunk * DM;
  const unsigned short* bptr0 = w1e + (size_t)(n0 + r0) * DM + kc;
  const unsigned short* bptr1 = bptr0 + (size_t)64 * DM;

  const int wrow = (wave >> 1) * 64;
  const int wcol = (wave & 1) * 64;
  const int lrow = lane & 15;
  // swizzled read k-offset (matches staging permutation; conflict-free)
  const int koff = ((lane >> 4) ^ ((lane >> 1) & 3)) * 8;

  f32x4 acc[4][4];
#pragma unroll
  for (int i = 0; i < 4; i++)
#pragma unroll
    for (int j = 0; j < 4; j++) acc[i][j] = (f32x4){0.f, 0.f, 0.f, 0.f};

#define STAGE1(bi, kk) do {                                   \
    unsigned short* A_ = As + (bi) * 4096 + wave * 512;       \
    unsigned short* B_ = Bs + (bi) * 4096 + wave * 512;       \
    async16(aptr0 + (kk), A_);                                \
    async16(aptr1 + (kk), A_ + 2048);                         \
    async16(bptr0 + (kk), B_);                                \
    async16(bptr1 + (kk), B_ + 2048);                         \
  } while (0)

#define COMPUTE1(bi) do {                                               \
    const unsigned short* A_ = As + (bi) * 4096;                        \
    const unsigned short* B_ = Bs + (bi) * 4096;                        \
    bf16x8 af[4], bfr[4];                                               \
    _Pragma("unroll")                                                   \
    for (int i = 0; i < 4; i++)                                         \
      af[i] = *(const bf16x8*)(A_ + (wrow + i * 16 + lrow) * 32 + koff);\
    _Pragma("unroll")                                                   \
    for (int j = 0; j < 4; j++)                                         \
      bfr[j] = *(const bf16x8*)(B_ + (wcol + j * 16 + lrow) * 32 + koff);\
    _Pragma("unroll")                                                   \
    for (int i = 0; i < 4; i++)                                         \
      _Pragma("unroll")                                                 \
      for (int j = 0; j < 4; j++)                                       \
        acc[i][j] = __builtin_amdgcn_mfma_f32_16x16x32_bf16(af[i], bfr[j], acc[i][j], 0, 0, 0); \
  } while (0)

  const int NS = DM / 32;   // 24 K-steps
  STAGE1(0, 0);
  STAGE1(1, 32);
  int cur = 0;
  for (int ts = 0; ts < NS - 2; ++ts) {
    int pf = cur + 2; if (pf >= 3) pf -= 3;
    STAGE1(pf, (ts + 2) * 32);
    asm volatile("s_waitcnt vmcnt(8)" ::: "memory");   // tile ts landed (own 4 oldest)
    __builtin_amdgcn_s_barrier();                       // landed for ALL waves
    COMPUTE1(cur);
    asm volatile("s_waitcnt lgkmcnt(0)" ::: "memory"); // reads retired before free
    __builtin_amdgcn_s_barrier();                       // buffer free for overwrite
    if (++cur == 3) cur = 0;
  }
  asm volatile("s_waitcnt vmcnt(4)" ::: "memory");
  __builtin_amdgcn_s_barrier();
  COMPUTE1(cur);
  if (++cur == 3) cur = 0;
  asm volatile("s_waitcnt vmcnt(0)" ::: "memory");
  __builtin_amdgcn_s_barrier();
  COMPUTE1(cur);

  // ---- epilogue: gelu + LDS-staged coalesced store (128B segments) ----
  __syncthreads();   // all waves done reading As/Bs; safe to reuse as C slab
  const int q4 = (lane >> 4) * 4;
  const int c = lane & 15;
  // per-wave slab: 64 rows x 72 shorts (144B rows -> 16B aligned reads)
  unsigned short* slab = (wave < 2) ? (As + wave * 4608) : (Bs + (wave - 2) * 4608);
#pragma unroll
  for (int j = 0; j < 4; j++) {
    const float bias = b1[e * HD + hoff + n0 + wcol + j * 16 + c];
#pragma unroll
    for (int i = 0; i < 4; i++) {
#pragma unroll
      for (int r = 0; r < 4; r++) {
        float v = acc[i][j][r] + bias;
        // exact identity: 0.5*v*(1+tanh(u)) == v * sigmoid(2u)
        float u2 = 1.5957691216f * (v + 0.044715f * v * v * v);
        float g = v / (1.f + __expf(-u2));
        slab[(i * 16 + q4 + r) * 72 + j * 16 + c] = f2bf(g);
      }
    }
  }
  asm volatile("s_waitcnt lgkmcnt(0)" ::: "memory");  // own writes visible (own slab only)
  const int l8 = lane & 7;
  const int r8 = lane >> 3;
  unsigned short* hrow = h + (size_t)(hb + m0 + wrow) * chunk + n0 + wcol;
#pragma unroll
  for (int p = 0; p < 8; p++) {
    int lm = p * 8 + r8;
    uint4 v = *(const uint4*)(slab + lm * 72 + l8 * 8);
    *(uint4*)(hrow + (size_t)lm * chunk + l8 * 8) = v;
  }
#undef STAGE1
#undef COMPUTE1
}

// -------- GEMM2 split-K: ye_part[kh][slot] = h_half @ w2_half (+ prev) ---------
// 256x256x32 tiles, 512 thr (8 waves 2Mx4N), 96KB 3-buf LDS, depth-2 counted
// vmcnt, kc XOR-swizzle. b = fast*WDIM2 + wi, fast = kh*3 + n-tile; XCD = wi%8.
__global__ __launch_bounds__(512) void gemm2_kernel(
    const unsigned short* __restrict__ h,     // [SLOTS_MAX][chunk] bf16
    const unsigned short* __restrict__ w2t,   // [E][DM][chunk] bf16
    const int* __restrict__ cnt,
    const int* __restrict__ base,
    const int2* __restrict__ wl,
    float* __restrict__ ye,                   // [2][SLOTS_MAX][DM] fp32
    int chunk, int add_prev) {
  const int b = blockIdx.x;
  const int wi = b % WDIM2;
  const int fast = b / WDIM2;            // 0..5
  const int2 wle = wl[wi];
  if (wle.x < 0) return;
  const int e = wle.x;
  const int m0 = wle.y;
  const int kh = fast / 3;
  const int n0 = (fast % 3) * 256;
  const int count = cnt[e];
  const int cpad = (count + 127) & ~127;
  const int hb = base[e];
  const int khalf = chunk >> 1;

  __shared__ unsigned short As[3 * 8192];
  __shared__ unsigned short Bs[3 * 8192];

  const int t = threadIdx.x;
  const int lane = t & 63;
  const int wave = t >> 6;
  const int r0 = t >> 2;
  const int kc = ((t & 3) ^ ((t >> 3) & 3)) * 8;

  const unsigned short* aptr0 = h + (size_t)(hb + m0 + r0) * chunk + kh * khalf + kc;
  const unsigned short* aptr1 = aptr0 + (size_t)128 * chunk;
  const unsigned short* w2e = w2t + (size_t)e * DM * chunk;
  const unsigned short* bptr0 = w2e + (size_t)(n0 + r0) * chunk + kh * khalf + kc;
  const unsigned short* bptr1 = bptr0 + (size_t)128 * chunk;

  const int wrow = (wave >> 2) * 128;
  const int wcol = (wave & 3) * 64;
  const int lrow = lane & 15;
  const int koff = ((lane >> 4) ^ ((lane >> 1) & 3)) * 8;

  f32x4 acc[8][4];
#pragma unroll
  for (int i = 0; i < 8; i++)
#pragma unroll
    for (int j = 0; j < 4; j++) acc[i][j] = (f32x4){0.f, 0.f, 0.f, 0.f};

#define STAGE2(bi, kk) do {                                   \
    unsigned short* A_ = As + (bi) * 8192 + wave * 512;       \
    unsigned short* B_ = Bs + (bi) * 8192 + wave * 512;       \
    async16(aptr0 + (kk), A_);                                \
    async16(aptr1 + (kk), A_ + 4096);                         \
    async16(bptr0 + (kk), B_);                                \
    async16(bptr1 + (kk), B_ + 4096);                         \
  } while (0)

#define COMPUTE2(bi) do {                                               \
    const unsigned short* A_ = As + (bi) * 8192;                        \
    const unsigned short* B_ = Bs + (bi) * 8192;                        \
    bf16x8 af[8], bfr[4];                                               \
    _Pragma("unroll")                                                   \
    for (int i = 0; i < 8; i++)                                         \
      af[i] = *(const bf16x8*)(A_ + (wrow + i * 16 + lrow) * 32 + koff);\
    _Pragma("unroll")                                                   \
    for (int j = 0; j < 4; j++)                                         \
      bfr[j] = *(const bf16x8*)(B_ + (wcol + j * 16 + lrow) * 32 + koff);\
    _Pragma("unroll")                                                   \
    for (int i = 0; i < 8; i++)                                         \
      _Pragma("unroll")                                                 \
      for (int j = 0; j < 4; j++)                                       \
        acc[i][j] = __builtin_amdgcn_mfma_f32_16x16x32_bf16(af[i], bfr[j], acc[i][j], 0, 0, 0); \
  } while (0)

  const int NS = khalf >> 5;
  STAGE2(0, 0);
  STAGE2(1, 32);
  int cur = 0;
  for (int ts = 0; ts < NS - 2; ++ts) {
    int pf = cur + 2; if (pf >= 3) pf -= 3;
    STAGE2(pf, (ts + 2) * 32);
    asm volatile("s_waitcnt vmcnt(8)" ::: "memory");
    __builtin_amdgcn_s_barrier();
    COMPUTE2(cur);
    asm volatile("s_waitcnt lgkmcnt(0)" ::: "memory");
    __builtin_amdgcn_s_barrier();
    if (++cur == 3) cur = 0;
  }
  asm volatile("s_waitcnt vmcnt(4)" ::: "memory");
  __builtin_amdgcn_s_barrier();
  COMPUTE2(cur);
  if (++cur == 3) cur = 0;
  asm volatile("s_waitcnt vmcnt(0)" ::: "memory");
  __builtin_amdgcn_s_barrier();
  COMPUTE2(cur);

  const int q4 = (lane >> 4) * 4;
  const int c = lane & 15;
  float* yrow = ye + (size_t)kh * SLOTS_MAX * DM + (size_t)(hb + m0) * DM + n0;
#pragma unroll
  for (int i = 0; i < 8; i++) {
#pragma unroll
    for (int r = 0; r < 4; r++) {
      int m = wrow + i * 16 + q4 + r;
      if (m0 + m < cpad) {
#pragma unroll
        for (int j = 0; j < 4; j++) {
          int n = wcol + j * 16 + c;
          float v = acc[i][j][r];
          if (add_prev) v += yrow[(size_t)m * DM + n];
          yrow[(size_t)m * DM + n] = v;
        }
      }
    }
  }
#undef STAGE2
#undef COMPUTE2
}

// ------- gather: out[tok] = s0*(ye0+ye1+b2)[gs0] + s1*(ye0+ye1+b2)[gs1] --------
__global__ void gather_kernel(const float* __restrict__ ye,
                              const float* __restrict__ b2,
                              const int2* __restrict__ tope,
                              const float2* __restrict__ tops,
                              const int2* __restrict__ pos,
                              const int* __restrict__ base,
                              float* __restrict__ out) {
  int idx = blockIdx.x * 256 + threadIdx.x;
  int tok = idx / (DM / 4);
  int d4 = (idx % (DM / 4)) * 4;
  int2 e = tope[tok];
  float2 s = tops[tok];
  int2 p = pos[tok];
  const float* ye1 = ye + (size_t)SLOTS_MAX * DM;
  float4 r = make_float4(0.f, 0.f, 0.f, 0.f);
  if (p.x < CAP) {
    size_t row = (size_t)(base[e.x] + p.x) * DM + d4;
    const float4 va = *(const float4*)(ye + row);
    const float4 vb = *(const float4*)(ye1 + row);
    const float4 bb = *(const float4*)(b2 + e.x * DM + d4);
    r.x += s.x * (va.x + vb.x + bb.x); r.y += s.x * (va.y + vb.y + bb.y);
    r.z += s.x * (va.z + vb.z + bb.z); r.w += s.x * (va.w + vb.w + bb.w);
  }
  if (p.y < CAP) {
    size_t row = (size_t)(base[e.y] + p.y) * DM + d4;
    const float4 va = *(const float4*)(ye + row);
    const float4 vb = *(const float4*)(ye1 + row);
    const float4 bb = *(const float4*)(b2 + e.y * DM + d4);
    r.x += s.y * (va.x + vb.x + bb.x); r.y += s.y * (va.y + vb.y + bb.y);
    r.z += s.y * (va.z + vb.z + bb.z); r.w += s.y * (va.w + vb.w + bb.w);
  }
  *(float4*)(out + (size_t)tok * DM + d4) = r;
}

extern "C" void kernel_launch(void* const* d_in, const int* in_sizes, int n_in,
                              void* d_out, int out_size, void* d_ws, size_t ws_size,
                              hipStream_t stream) {
  const float* inp = (const float*)d_in[0];
  const float* gw  = (const float*)d_in[1];
  const float* gb  = (const float*)d_in[2];
  const float* w1  = (const float*)d_in[3];
  const float* b1  = (const float*)d_in[4];
  const float* w2  = (const float*)d_in[5];
  const float* b2  = (const float*)d_in[6];
  float* out = (float*)d_out;

  const size_t meta = 165376;
  // chunk selection with DUAL wt buffers (w1t and w2t live simultaneously so
  // both transposes can run inside one fused kernel). chunk mult of 256.
  const int cands[6] = {3072, 1536, 1024, 768, 512, 256};
  int chunk = 256;
  for (int ci = 0; ci < 6; ci++) {
    int c = cands[ci];
    size_t need = meta + (size_t)NT * DM * 2                 // xb
                + 2 * (size_t)NE * c * DM * 2                // w1t + w2t
                + (size_t)SLOTS_MAX * c * 2                  // h
                + 2 * (size_t)SLOTS_MAX * DM * 4;            // ye (2 partials)
    if (need <= ws_size) { chunk = c; break; }
  }

  char* ws = (char*)d_ws;
  int*    cnt  = (int*)(ws);              // 256 B
  int*    base = (int*)(ws + 256);        // 256 B
  int*    srcb = (int*)(ws + 512);        // 64 KB  -> 66048
  int2*   tope = (int2*)(ws + 66048);     // 32 KB  -> 98816
  float2* tops = (float2*)(ws + 98816);   // 32 KB  -> 131584
  int2*   pos  = (int2*)(ws + 131584);    // 32 KB  -> 164352
  int2*   wl1  = (int2*)(ws + 164352);    // 576 B (72 entries)
  int2*   wl2  = (int2*)(ws + 164928);    // 320 B (40 entries)
  size_t off = meta;
  unsigned short* xb  = (unsigned short*)(ws + off);  off += (size_t)NT * DM * 2;
  unsigned short* w1t = (unsigned short*)(ws + off);  off += (size_t)NE * chunk * DM * 2;
  unsigned short* w2t = (unsigned short*)(ws + off);  off += (size_t)NE * chunk * DM * 2;
  unsigned short* hc  = (unsigned short*)(ws + off);  off += (size_t)SLOTS_MAX * chunk * 2;
  float* ye = (float*)(ws + off);

  const int ngate = NT / 4;                                 // 1024
  const int nt1 = NE * (chunk / 64) * (DM / 256);           // w1 tiles
  const int nt2 = NE * (DM / 64) * (chunk / 256);           // w2 tiles

  // fused front-end: (gate + x-convert) || w1-transpose(c0) || w2-transpose(c0)
  prep_kernel<<<ngate + nt1 + nt2, 256, 0, stream>>>(
      inp, xb, gw, gb, tope, tops, w1, w1t, w2, w2t,
      chunk, ngate, nt1);
  assign_kernel<<<1, 1024, 0, stream>>>(tope, cnt, base, srcb, pos, wl1, wl2);

  for (int c = 0; c < HD; c += chunk) {
    if (c > 0)
      transpose_both_kernel<<<nt1 + nt2, 256, 0, stream>>>(
          w1, w1t, w2, w2t, chunk, c, nt1);
    gemm1_kernel<<<(chunk / 128) * WDIM1, 256, 0, stream>>>(
        xb, w1t, b1, cnt, base, srcb, wl1, hc, c, chunk);
    gemm2_kernel<<<(2 * DM / 256) * WDIM2, 512, 0, stream>>>(
        hc, w2t, cnt, base, wl2, ye, chunk, c == 0 ? 0 : 1);
  }

  gather_kernel<<<(NT * DM / 4) / 256, 256, 0, stream>>>(ye, b2, tope, tops, pos, base, out);
}